// Round 20
// baseline (1986.244 us; speedup 1.0000x reference)
//
#include <hip/hip_runtime.h>

#define SEQ 2048
#define DMODEL 1024
#define DINNER 2048
#define DSTATE 16
#define DTRANK 64
#define NLAYER 8
#define VOCAB 32000
#define NCHUNK 32
#define CLEN 64   // SEQ / NCHUNK
#define PZ 16     // split-K chunks for the projection GEMM

typedef float f32x4 __attribute__((ext_vector_type(4)));
typedef short bf16x8 __attribute__((ext_vector_type(8)));

__device__ __forceinline__ ushort f2bf(float f) {
  union { float f; unsigned u; } v; v.f = f;
  unsigned r = v.u + 0x7fffu + ((v.u >> 16) & 1u);
  return (ushort)(r >> 16);
}
__device__ __forceinline__ float bf2f(ushort b) {
  union { unsigned u; float f; } v; v.u = ((unsigned)b) << 16;
  return v.f;
}

__device__ __forceinline__ void lds_load16(const void* g, void* l) {
  __builtin_amdgcn_global_load_lds(
      (const __attribute__((address_space(1))) void*)g,
      (__attribute__((address_space(3))) void*)l, 16, 0, 0);
}

// ---------------- 256x256 counted-vmcnt MFMA GEMM (proven ~197us logits) ----
template<int BM, bool NTS>
__global__ __launch_bounds__(512, 2) void gemm8p_bt_bf16(
    const ushort* __restrict__ A, const ushort* __restrict__ B,
    float* __restrict__ C, int N, int K)
{
  constexpr int MFR = BM / 32;
  constexpr int MPP = MFR / 4;
  constexpr int ALOADS = BM / 128;
  __shared__ __align__(16) ushort As[2 * BM * 64];
  __shared__ __align__(16) ushort Bs[2 * 256 * 64];
  const int tid = threadIdx.x;
  const int lane = tid & 63;
  const int wid = tid >> 6;
  const int wr = wid >> 2, wc = wid & 3;
  const int rr = lane & 15, kq = lane >> 4;

  unsigned nwg = gridDim.x * gridDim.y;
  unsigned lb = blockIdx.y * gridDim.x + blockIdx.x;
  if ((nwg & 7u) == 0u) { unsigned cpx = nwg >> 3; lb = (lb & 7u) * cpx + (lb >> 3); }
  const int bm = (int)(lb % gridDim.x) * BM;
  const int bn = (int)(lb / gridDim.x) * 256;

  const ushort* Abase = A + (size_t)bm * K;
  const ushort* Bbase = B + (size_t)bn * K;

  auto stageA = [&](int buf, int h, int kt) {
    constexpr int HR = BM / 2;
#pragma unroll
    for (int L = 0; L < ALOADS; ++L) {
      int f = L * 512 + tid;
      int rl = f >> 3, g = f & 7;
      int gg = g ^ (rl & 7);
      lds_load16(Abase + (size_t)(h * HR + rl) * K + kt * 64 + gg * 8,
                 (void*)(As + buf * (BM * 64) + (h * HR + rl) * 64 + g * 8));
    }
  };
  auto stageB = [&](int buf, int h, int kt) {
#pragma unroll
    for (int L = 0; L < 2; ++L) {
      int f = L * 512 + tid;
      int rl = f >> 3, g = f & 7;
      int gg = g ^ (rl & 7);
      lds_load16(Bbase + (size_t)(h * 128 + rl) * K + kt * 64 + gg * 8,
                 (void*)(Bs + buf * (256 * 64) + (h * 128 + rl) * 64 + g * 8));
    }
  };
  auto rdA = [&](int buf, int r, int kbyte) {
    int sw = kbyte ^ ((r & 7) << 4);
    return *(const bf16x8*)(As + buf * (BM * 64) + r * 64 + (sw >> 1));
  };
  auto rdB = [&](int buf, int r, int kbyte) {
    int sw = kbyte ^ ((r & 7) << 4);
    return *(const bf16x8*)(Bs + buf * (256 * 64) + r * 64 + (sw >> 1));
  };

  f32x4 acc[MFR][4];
#pragma unroll
  for (int m = 0; m < MFR; ++m)
#pragma unroll
    for (int n = 0; n < 4; ++n) acc[m][n] = (f32x4){0.f, 0.f, 0.f, 0.f};

  const int NT = K >> 6;
  stageA(0, 0, 0); stageA(0, 1, 0); stageB(0, 0, 0); stageB(0, 1, 0);

  for (int t = 0; t < NT; ++t) {
    const int cur = t & 1;
    const bool more = (t + 1 < NT);
    if (more) stageA(cur ^ 1, 0, t + 1);
    if (more) {
      if constexpr (BM == 256) asm volatile("s_waitcnt vmcnt(2)" ::: "memory");
      else                     asm volatile("s_waitcnt vmcnt(1)" ::: "memory");
    } else {
      asm volatile("s_waitcnt vmcnt(0)" ::: "memory");
    }
    __syncthreads();

    bf16x8 bfr[4][2];
#pragma unroll
    for (int n = 0; n < 4; ++n)
#pragma unroll
      for (int kk = 0; kk < 2; ++kk)
        bfr[n][kk] = rdB(cur, wc * 64 + n * 16 + rr, kk * 64 + kq * 16);

#pragma unroll
    for (int mq = 0; mq < 4; ++mq) {
      if (mq == 1 && more) stageA(cur ^ 1, 1, t + 1);
      if (mq == 2 && more) stageB(cur ^ 1, 0, t + 1);
      if (mq == 3 && more) stageB(cur ^ 1, 1, t + 1);
      bf16x8 af[MPP][2];
#pragma unroll
      for (int mf = 0; mf < MPP; ++mf)
#pragma unroll
        for (int kk = 0; kk < 2; ++kk)
          af[mf][kk] = rdA(cur, wr * (BM / 2) + (mq * MPP + mf) * 16 + rr, kk * 64 + kq * 16);
      __builtin_amdgcn_s_setprio(1);
#pragma unroll
      for (int kk = 0; kk < 2; ++kk)
#pragma unroll
        for (int mf = 0; mf < MPP; ++mf)
#pragma unroll
          for (int n = 0; n < 4; ++n)
            acc[mq * MPP + mf][n] = __builtin_amdgcn_mfma_f32_16x16x32_bf16(
                af[mf][kk], bfr[n][kk], acc[mq * MPP + mf][n], 0, 0, 0);
      __builtin_amdgcn_s_setprio(0);
    }
    __syncthreads();
  }

  float* ep = (float*)Bs + wid * (16 * 68);
  const int cg = bn + wc * 64;
#pragma unroll
  for (int m = 0; m < MFR; ++m) {
    const int r0g = bm + wr * (BM / 2) + m * 16;
#pragma unroll
    for (int n = 0; n < 4; ++n)
#pragma unroll
      for (int j = 0; j < 4; ++j)
        ep[(kq * 4 + j) * 68 + n * 16 + rr] = acc[m][n][j];
#pragma unroll
    for (int i = 0; i < 4; ++i) {
      int row = i * 4 + kq;
      f32x4 v = *(const f32x4*)&ep[row * 68 + rr * 4];
      f32x4* dst = (f32x4*)&C[(size_t)(r0g + row) * N + cg + rr * 4];
      if constexpr (NTS) __builtin_nontemporal_store(v, dst);
      else *dst = v;
    }
  }
}

// ---------------- 128x128 2-blocks/CU MFMA GEMM (layer gemm1) ---------------
template<bool OUTBF>
__global__ __launch_bounds__(256, 2) void gemm2p_bt_bf16(
    const ushort* __restrict__ A, const ushort* __restrict__ B,
    void* __restrict__ Cv, int N, int K)
{
  __shared__ __align__(16) ushort As[2 * 128 * 64];
  __shared__ __align__(16) ushort Bs[2 * 128 * 64];
  const int tid = threadIdx.x;
  const int lane = tid & 63;
  const int wave = tid >> 6;
  const int wr = wave >> 1, wc = wave & 1;
  const int rr = lane & 15, kq = lane >> 4;

  unsigned nwg = gridDim.x * gridDim.y;
  unsigned lb = blockIdx.y * gridDim.x + blockIdx.x;
  if ((nwg & 7u) == 0u) { unsigned cpx = nwg >> 3; lb = (lb & 7u) * cpx + (lb >> 3); }
  const int bm = (int)(lb % gridDim.x) * 128;
  const int bn = (int)(lb / gridDim.x) * 128;

  const ushort* Abase = A + (size_t)bm * K;
  const ushort* Bbase = B + (size_t)bn * K;

  auto stage = [&](int buf, int kt) {
#pragma unroll
    for (int i = 0; i < 4; ++i) {
      int f = i * 256 + tid;
      int rl = f >> 3, g = f & 7;
      int gg = g ^ (rl & 7);
      lds_load16(Abase + (size_t)rl * K + kt * 64 + gg * 8,
                 (void*)(As + buf * 8192 + rl * 64 + g * 8));
      lds_load16(Bbase + (size_t)rl * K + kt * 64 + gg * 8,
                 (void*)(Bs + buf * 8192 + rl * 64 + g * 8));
    }
  };
  auto rdA = [&](int buf, int r, int kbyte) {
    int sw = kbyte ^ ((r & 7) << 4);
    return *(const bf16x8*)(As + buf * 8192 + r * 64 + (sw >> 1));
  };
  auto rdB = [&](int buf, int r, int kbyte) {
    int sw = kbyte ^ ((r & 7) << 4);
    return *(const bf16x8*)(Bs + buf * 8192 + r * 64 + (sw >> 1));
  };

  f32x4 acc[4][4];
#pragma unroll
  for (int m = 0; m < 4; ++m)
#pragma unroll
    for (int n = 0; n < 4; ++n) acc[m][n] = (f32x4){0.f, 0.f, 0.f, 0.f};

  const int NT = K >> 6;
  stage(0, 0);

  for (int t = 0; t < NT; ++t) {
    const int cur = t & 1;
    if (t + 1 < NT) {
      stage(cur ^ 1, t + 1);
      asm volatile("s_waitcnt vmcnt(8)" ::: "memory");
    } else {
      asm volatile("s_waitcnt vmcnt(0)" ::: "memory");
    }
    __syncthreads();
#pragma unroll
    for (int ks = 0; ks < 2; ++ks) {
      const int kbyte = ks * 64 + kq * 16;
      bf16x8 af[4], bfr[4];
#pragma unroll
      for (int m = 0; m < 4; ++m)
        af[m] = rdA(cur, wr * 64 + m * 16 + rr, kbyte);
#pragma unroll
      for (int n = 0; n < 4; ++n)
        bfr[n] = rdB(cur, wc * 64 + n * 16 + rr, kbyte);
      __builtin_amdgcn_s_setprio(1);
#pragma unroll
      for (int m = 0; m < 4; ++m)
#pragma unroll
        for (int n = 0; n < 4; ++n)
          acc[m][n] = __builtin_amdgcn_mfma_f32_16x16x32_bf16(af[m], bfr[n], acc[m][n], 0, 0, 0);
      __builtin_amdgcn_s_setprio(0);
    }
    __syncthreads();
  }

  float* ep = (float*)Bs + wave * (16 * 68);
  const int cg = bn + wc * 64;
#pragma unroll
  for (int m = 0; m < 4; ++m) {
    const int r0g = bm + wr * 64 + m * 16;
#pragma unroll
    for (int n = 0; n < 4; ++n)
#pragma unroll
      for (int j = 0; j < 4; ++j)
        ep[(kq * 4 + j) * 68 + n * 16 + rr] = acc[m][n][j];
#pragma unroll
    for (int i = 0; i < 4; ++i) {
      int row = i * 4 + kq;
      f32x4 v = *(const f32x4*)&ep[row * 68 + rr * 4];
      if constexpr (OUTBF) {
        ushort* C = (ushort*)Cv;
        ushort4 o = {f2bf(v.x), f2bf(v.y), f2bf(v.z), f2bf(v.w)};
        *(ushort4*)&C[(size_t)(r0g + row) * N + cg + rr * 4] = o;
      } else {
        float* C = (float*)Cv;
        *(f32x4*)&C[(size_t)(r0g + row) * N + cg + rr * 4] = v;
      }
    }
  }
}

// ---- split-K bf16 MFMA GEMM (2-phase 128x128, T2 swizzle, bf16 partials) ---
__global__ __launch_bounds__(256) void gemm_btk_bf16(
    const ushort* __restrict__ A, const ushort* __restrict__ B,
    ushort* __restrict__ Cp, int M, int N, int K)
{
  __shared__ __align__(16) ushort As[128 * 64];
  __shared__ __align__(16) ushort Bs[128 * 64];
  const int tid = threadIdx.x;
  const int lane = tid & 63;
  const int wave = tid >> 6;
  const int wr = wave >> 1, wc = wave & 1;
  const int KC = K / gridDim.z;
  const int k0 = blockIdx.z * KC;

  unsigned nwg = gridDim.x * gridDim.y;
  unsigned lb = blockIdx.y * gridDim.x + blockIdx.x;
  if ((nwg & 7u) == 0u) {
    unsigned cpx = nwg >> 3;
    lb = (lb & 7u) * cpx + (lb >> 3);
  }
  const int bm = (lb % gridDim.x) * 128;
  const int bn = (lb / gridDim.x) * 128;
  const int rr = lane & 15, kq = lane >> 4;

  auto rdA = [&](int r, int kbyte) {
    int sw = kbyte ^ ((r & 7) << 4);
    return *(const bf16x8*)(As + r * 64 + (sw >> 1));
  };
  auto rdB = [&](int r, int kbyte) {
    int sw = kbyte ^ ((r & 7) << 4);
    return *(const bf16x8*)(Bs + r * 64 + (sw >> 1));
  };

  f32x4 acc[4][4];
#pragma unroll
  for (int m = 0; m < 4; ++m)
#pragma unroll
    for (int n = 0; n < 4; ++n) acc[m][n] = (f32x4){0.f, 0.f, 0.f, 0.f};

  for (int kt = 0; kt < KC; kt += 64) {
#pragma unroll
    for (int i = 0; i < 4; ++i) {
      int fb = i * 256 + tid;
      int row = fb >> 3, g = fb & 7;
      int gg = g ^ (row & 7);
      lds_load16(A + (size_t)(bm + row) * K + k0 + kt + gg * 8, (void*)(As + (size_t)fb * 8));
      lds_load16(B + (size_t)(bn + row) * K + k0 + kt + gg * 8, (void*)(Bs + (size_t)fb * 8));
    }
    asm volatile("s_waitcnt vmcnt(0)" ::: "memory");
    __syncthreads();
#pragma unroll
    for (int ks = 0; ks < 2; ++ks) {
      const int kbyte = ks * 64 + kq * 16;
      bf16x8 af[4], bfr[4];
#pragma unroll
      for (int m = 0; m < 4; ++m)
        af[m] = rdA(wr * 64 + m * 16 + rr, kbyte);
#pragma unroll
      for (int n = 0; n < 4; ++n)
        bfr[n] = rdB(wc * 64 + n * 16 + rr, kbyte);
#pragma unroll
      for (int m = 0; m < 4; ++m)
#pragma unroll
        for (int n = 0; n < 4; ++n)
          acc[m][n] = __builtin_amdgcn_mfma_f32_16x16x32_bf16(af[m], bfr[n], acc[m][n], 0, 0, 0);
    }
    __syncthreads();
  }
  ushort* C = Cp + (size_t)blockIdx.z * M * N;
#pragma unroll
  for (int m = 0; m < 4; ++m) {
    const int r0 = bm + wr * 64 + m * 16 + kq * 4;
#pragma unroll
    for (int n = 0; n < 4; ++n) {
      const int cc = bn + wc * 64 + n * 16 + rr;
#pragma unroll
      for (int j = 0; j < 4; ++j)
        C[(size_t)(r0 + j) * N + cc] = f2bf(acc[m][n][j]);
    }
  }
}

// ---------------- fused conv+SiLU + split-K MFMA projection (T2 swizzle) ----
__global__ __launch_bounds__(256) void convproj_mfma(
    const ushort* __restrict__ resu0, const ushort* __restrict__ W,
    const float* __restrict__ Wconv, ushort* __restrict__ u,
    float* __restrict__ Cp, int M)
{
  __shared__ __align__(16) ushort u0s[131][128];
  __shared__ __align__(16) ushort As[2][128 * 64];
  __shared__ __align__(16) ushort Bs[2][128 * 64];
  const int tid = threadIdx.x;
  const int lane = tid & 63;
  const int wave = tid >> 6;
  const int wr = wave >> 1, wc = wave & 1;
  const int rr = lane & 15, kq = lane >> 4;
  const int bm = blockIdx.x * 128;
  const int kc = blockIdx.z * 128;

#pragma unroll
  for (int h = 0; h < 2; ++h)
#pragma unroll
    for (int i = 0; i < 4; ++i) {
      int f = i * 256 + tid;
      int rl = f >> 3, g = f & 7;
      int gg = g ^ (rl & 7);
      lds_load16(W + (size_t)rl * DINNER + kc + h * 64 + gg * 8,
                 (void*)(&Bs[h][rl * 64 + g * 8]));
    }

  for (int i = tid; i < 131 * 32; i += 256) {
    int row = i >> 5, c4 = (i & 31) * 4;
    int gr = bm - 3 + row;
    ushort4 v = {0, 0, 0, 0};
    if (gr >= 0)
      v = *(const ushort4*)&resu0[(size_t)gr * (2 * DINNER) + DINNER + kc + c4];
    *(ushort4*)&u0s[row][c4] = v;
  }
  __syncthreads();

  {
    const int c0 = (tid & 31) * 4;
    const int r0 = (tid >> 5) * 16;
    float4 w0 = *(const float4*)&Wconv[(kc + c0 + 0) * 4];
    float4 w1 = *(const float4*)&Wconv[(kc + c0 + 1) * 4];
    float4 w2 = *(const float4*)&Wconv[(kc + c0 + 2) * 4];
    float4 w3 = *(const float4*)&Wconv[(kc + c0 + 3) * 4];
    const int ks = c0 >> 6;
    const int cl = c0 & 63;
    for (int r = r0; r < r0 + 16; ++r) {
      ushort4 a0 = *(const ushort4*)&u0s[r + 0][c0];
      ushort4 a1 = *(const ushort4*)&u0s[r + 1][c0];
      ushort4 a2 = *(const ushort4*)&u0s[r + 2][c0];
      ushort4 a3 = *(const ushort4*)&u0s[r + 3][c0];
      float o0 = bf2f(a0.x) * w0.x + bf2f(a1.x) * w0.y + bf2f(a2.x) * w0.z + bf2f(a3.x) * w0.w;
      float o1 = bf2f(a0.y) * w1.x + bf2f(a1.y) * w1.y + bf2f(a2.y) * w1.z + bf2f(a3.y) * w1.w;
      float o2 = bf2f(a0.z) * w2.x + bf2f(a1.z) * w2.y + bf2f(a2.z) * w2.z + bf2f(a3.z) * w2.w;
      float o3 = bf2f(a0.w) * w3.x + bf2f(a1.w) * w3.y + bf2f(a2.w) * w3.z + bf2f(a3.w) * w3.w;
      o0 = o0 / (1.f + expf(-o0));
      o1 = o1 / (1.f + expf(-o1));
      o2 = o2 / (1.f + expf(-o2));
      o3 = o3 / (1.f + expf(-o3));
      ushort4 o = {f2bf(o0), f2bf(o1), f2bf(o2), f2bf(o3)};
      int sg = ((cl >> 3) ^ (r & 7)) * 8 + (cl & 7);
      *(ushort4*)&As[ks][r * 64 + sg] = o;
      *(ushort4*)&u[(size_t)(bm + r) * DINNER + kc + c0] = o;
    }
  }
  asm volatile("s_waitcnt vmcnt(0)" ::: "memory");
  __syncthreads();

  f32x4 acc[4][4];
#pragma unroll
  for (int m = 0; m < 4; ++m)
#pragma unroll
    for (int n = 0; n < 4; ++n) acc[m][n] = (f32x4){0.f, 0.f, 0.f, 0.f};

#pragma unroll
  for (int ks = 0; ks < 2; ++ks) {
#pragma unroll
    for (int kk = 0; kk < 2; ++kk) {
      const int kbyte = kk * 64 + kq * 16;
      bf16x8 af[4], bfr[4];
#pragma unroll
      for (int m = 0; m < 4; ++m) {
        int r = wr * 64 + m * 16 + rr;
        int sw = kbyte ^ ((r & 7) << 4);
        af[m] = *(const bf16x8*)&As[ks][r * 64 + (sw >> 1)];
      }
#pragma unroll
      for (int n = 0; n < 4; ++n) {
        int r = wc * 64 + n * 16 + rr;
        int sw = kbyte ^ ((r & 7) << 4);
        bfr[n] = *(const bf16x8*)&Bs[ks][r * 64 + (sw >> 1)];
      }
      __builtin_amdgcn_s_setprio(1);
#pragma unroll
      for (int m = 0; m < 4; ++m)
#pragma unroll
        for (int n = 0; n < 4; ++n)
          acc[m][n] = __builtin_amdgcn_mfma_f32_16x16x32_bf16(af[m], bfr[n], acc[m][n], 0, 0, 0);
      __builtin_amdgcn_s_setprio(0);
    }
  }

  float* C = Cp + (size_t)blockIdx.z * M * 128;
#pragma unroll
  for (int m = 0; m < 4; ++m) {
    const int r0 = bm + wr * 64 + m * 16 + kq * 4;
#pragma unroll
    for (int n = 0; n < 4; ++n) {
      const int cc = wc * 64 + n * 16 + rr;
#pragma unroll
      for (int j = 0; j < 4; ++j)
        C[(size_t)(r0 + j) * 128 + cc] = acc[m][n][j];
    }
  }
}

// ---- x += P0 + P1 (bf16 partials), then RMSNorm(x)->bf16 (or plain cast) ---
__global__ __launch_bounds__(256) void add3_rms_kernel(
    const ushort* __restrict__ P0, const ushort* __restrict__ P1,
    float* __restrict__ x, ushort* __restrict__ dst, int donorm)
{
  size_t o = (size_t)blockIdx.x * (DMODEL / 4) + threadIdx.x;
  ushort4 a = ((const ushort4*)P0)[o];
  ushort4 b = ((const ushort4*)P1)[o];
  float4 c = ((float4*)x)[o];
  c.x += bf2f(a.x) + bf2f(b.x);
  c.y += bf2f(a.y) + bf2f(b.y);
  c.z += bf2f(a.z) + bf2f(b.z);
  c.w += bf2f(a.w) + bf2f(b.w);
  ((float4*)x)[o] = c;
  float sc = 1.f;
  if (donorm) {
    float s = c.x * c.x + c.y * c.y + c.z * c.z + c.w * c.w;
#pragma unroll
    for (int off = 32; off > 0; off >>= 1) s += __shfl_down(s, off);
    __shared__ float ws[4];
    if ((threadIdx.x & 63) == 0) ws[threadIdx.x >> 6] = s;
    __syncthreads();
    float tot = ws[0] + ws[1] + ws[2] + ws[3];
    sc = rsqrtf(tot * (1.0f / DMODEL) + 1e-6f);
  }
  ushort4 o4 = {f2bf(c.x * sc), f2bf(c.y * sc), f2bf(c.z * sc), f2bf(c.w * sc)};
  ((ushort4*)dst)[o] = o4;
}

// ---------------- embedding gather + RMSNorm -> x (f32) and xnb (bf16) ------
__global__ __launch_bounds__(256) void gather_rms_kernel(
    const int* __restrict__ ids, const float* __restrict__ embed,
    float* __restrict__ x, ushort* __restrict__ xnb)
{
  int row = blockIdx.x;
  int id = ids[row];
  float4 v = ((const float4*)(embed + (size_t)id * DMODEL))[threadIdx.x];
  size_t o = (size_t)row * (DMODEL / 4) + threadIdx.x;
  ((float4*)x)[o] = v;
  float s = v.x * v.x + v.y * v.y + v.z * v.z + v.w * v.w;
#pragma unroll
  for (int off = 32; off > 0; off >>= 1) s += __shfl_down(s, off);
  __shared__ float ws[4];
  if ((threadIdx.x & 63) == 0) ws[threadIdx.x >> 6] = s;
  __syncthreads();
  float tot = ws[0] + ws[1] + ws[2] + ws[3];
  float sc = rsqrtf(tot * (1.0f / DMODEL) + 1e-6f);
  ushort4 o4 = {f2bf(v.x * sc), f2bf(v.y * sc), f2bf(v.z * sc), f2bf(v.w * sc)};
  ((ushort4*)xnb)[o] = o4;
}

// ---- proj reduce: B/C -> bcdt f32 (cols 0..31), dt-in -> dtinb bf16 --------
__global__ __launch_bounds__(256) void proj_reduce(
    const float* __restrict__ Cp, float* __restrict__ bcdt,
    ushort* __restrict__ dtinb, int M)
{
  int idx = blockIdx.x * 256 + threadIdx.x;
  int row = idx / 96, col = idx - row * 96;
  float s = 0.f;
#pragma unroll
  for (int c = 0; c < PZ; ++c) s += Cp[(size_t)c * M * 128 + (size_t)row * 128 + col];
  if (col < 32) bcdt[(size_t)row * 96 + col] = s;
  else dtinb[(size_t)row * 64 + (col - 32)] = f2bf(s);
}

// ---- in-block dt tile: sdt[64 t][16 d] = softplus(dtin @ W2^T + bdt) -------
// 4 waves, each computes one 16-row m-fragment via 2 MFMAs (M=64,N=16,K=64).
__device__ __forceinline__ void compute_dt_tile(
    const ushort* sDtin /*[64*64]*/, const ushort* sW2 /*[16*64]*/,
    const float* __restrict__ bdt, int dbase,
    float sdt[CLEN][16], int tid)
{
  const int wave = tid >> 6;
  const int lane = tid & 63;
  f32x4 dacc = (f32x4){0.f, 0.f, 0.f, 0.f};
#pragma unroll
  for (int ks = 0; ks < 2; ++ks) {
    bf16x8 af = *(const bf16x8*)&sDtin[(wave * 16 + (lane & 15)) * 64 + ks * 32 + (lane >> 4) * 8];
    bf16x8 bf = *(const bf16x8*)&sW2[(lane & 15) * 64 + ks * 32 + (lane >> 4) * 8];
    dacc = __builtin_amdgcn_mfma_f32_16x16x32_bf16(af, bf, dacc, 0, 0, 0);
  }
  const int col = lane & 15;                 // d index within tile
  const float bv = bdt[dbase + col];
#pragma unroll
  for (int j = 0; j < 4; ++j) {
    int trow = wave * 16 + (lane >> 4) * 4 + j;
    float v = dacc[j] + bv;
    v = (v > 20.f) ? v : log1pf(expf(v));
    sdt[trow][col] = v;
  }
}

// ---------------- chunk-parallel selective scan (dt fused via MFMA) ---------
__global__ __launch_bounds__(256) void scan_pass1(
    const ushort* __restrict__ dtinb, const ushort* __restrict__ u,
    const float* __restrict__ bcdt, const ushort* __restrict__ wdt2,
    const float* __restrict__ bdt, const float* __restrict__ logA,
    float* __restrict__ P, float* __restrict__ S)
{
  const int tid = threadIdx.x;
  const int n = tid & 15, dl = tid >> 4;
  const int dbase = blockIdx.x * 16;
  const int c = blockIdx.y;
  const int t0 = c * CLEN;
  const int d = dbase + dl;
  const float Aval = -expf(logA[d * DSTATE + n]);
  __shared__ float sdt[CLEN][16], su[CLEN][16], sB[CLEN][16];
  __shared__ __align__(16) ushort sDtin[64 * 64];
  __shared__ __align__(16) ushort sW2[16 * 64];
  {
    int tt = tid >> 2, j0 = (tid & 3) * 4;
    ushort4 ru = *(const ushort4*)&u[(size_t)(t0 + tt) * DINNER + dbase + j0];
    su[tt][j0 + 0] = bf2f(ru.x); su[tt][j0 + 1] = bf2f(ru.y);
    su[tt][j0 + 2] = bf2f(ru.z); su[tt][j0 + 3] = bf2f(ru.w);
    *(float4*)&sB[tt][j0] = *(const float4*)&bcdt[(size_t)(t0 + tt) * 96 + j0];
  }
  for (int i = tid; i < 64 * 16; i += 256) {
    int row = i >> 4, c4 = (i & 15) * 4;
    *(ushort4*)&sDtin[row * 64 + c4] = *(const ushort4*)&dtinb[(size_t)(t0 + row) * 64 + c4];
  }
  if (tid < 16 * 16) {
    int row = tid >> 4, c4 = (tid & 15) * 4;
    *(ushort4*)&sW2[row * 64 + c4] = *(const ushort4*)&wdt2[(size_t)(dbase + row) * DTRANK + c4];
  }
  __syncthreads();
  compute_dt_tile(sDtin, sW2, bdt, dbase, sdt, tid);
  __syncthreads();
  float h = 0.f, pr = 1.f;
#pragma unroll 8
  for (int i = 0; i < CLEN; ++i) {
    float dtv = sdt[i][dl], uv = su[i][dl], Bv = sB[i][n];
    float dtA = dtv * Aval;
    float rinv = __builtin_amdgcn_rcpf(1.f - 0.5f * dtA);
    float dA = (1.f + 0.5f * dtA) * rinv;
    float dBu = dtv * Bv * rinv * uv;
    h = dA * h + dBu;
    pr *= dA;
  }
  size_t idx = (size_t)c * (DINNER * DSTATE) + (size_t)d * DSTATE + n;
  P[idx] = pr;
  S[idx] = h;
}

__global__ __launch_bounds__(256) void scan_pass2(
    const ushort* __restrict__ dtinb, const ushort* __restrict__ u,
    const float* __restrict__ bcdt, const ushort* __restrict__ wdt2,
    const float* __restrict__ bdt, const float* __restrict__ logA,
    const float* __restrict__ Dp, const float* __restrict__ P,
    const float* __restrict__ S, const ushort* __restrict__ resu0,
    ushort* __restrict__ y2b)
{
  const int tid = threadIdx.x;
  const int n = tid & 15, dl = tid >> 4;
  const int dbase = blockIdx.x * 16;
  const int c = blockIdx.y;
  const int t0 = c * CLEN;
  const int d = dbase + dl;
  const float Aval = -expf(logA[d * DSTATE + n]);
  const float Dpv = Dp[d];
  __shared__ float sdt[CLEN][16], su[CLEN][16], sB[CLEN][16], sC[CLEN][16], sres[CLEN][16];
  __shared__ __align__(16) ushort sDtin[64 * 64];
  __shared__ __align__(16) ushort sW2[16 * 64];
  {
    int tt = tid >> 2, j0 = (tid & 3) * 4;
    ushort4 ru = *(const ushort4*)&u[(size_t)(t0 + tt) * DINNER + dbase + j0];
    ushort4 rr4 = *(const ushort4*)&resu0[(size_t)(t0 + tt) * (2 * DINNER) + dbase + j0];
    su[tt][j0 + 0] = bf2f(ru.x); su[tt][j0 + 1] = bf2f(ru.y);
    su[tt][j0 + 2] = bf2f(ru.z); su[tt][j0 + 3] = bf2f(ru.w);
    sres[tt][j0 + 0] = bf2f(rr4.x); sres[tt][j0 + 1] = bf2f(rr4.y);
    sres[tt][j0 + 2] = bf2f(rr4.z); sres[tt][j0 + 3] = bf2f(rr4.w);
    *(float4*)&sB[tt][j0] = *(const float4*)&bcdt[(size_t)(t0 + tt) * 96 + j0];
    *(float4*)&sC[tt][j0] = *(const float4*)&bcdt[(size_t)(t0 + tt) * 96 + 16 + j0];
  }
  for (int i = tid; i < 64 * 16; i += 256) {
    int row = i >> 4, c4 = (i & 15) * 4;
    *(ushort4*)&sDtin[row * 64 + c4] = *(const ushort4*)&dtinb[(size_t)(t0 + row) * 64 + c4];
  }
  if (tid < 16 * 16) {
    int row = tid >> 4, c4 = (tid & 15) * 4;
    *(ushort4*)&sW2[row * 64 + c4] = *(const ushort4*)&wdt2[(size_t)(dbase + row) * DTRANK + c4];
  }
  float h = 0.f;
  {
    const size_t base = (size_t)d * DSTATE + n;
#pragma unroll 4
    for (int cc = 0; cc < c; ++cc) {
      size_t o = (size_t)cc * (DINNER * DSTATE) + base;
      h = P[o] * h + S[o];
    }
  }
  __syncthreads();
  compute_dt_tile(sDtin, sW2, bdt, dbase, sdt, tid);
  __syncthreads();
#pragma unroll 4
  for (int i = 0; i < CLEN; ++i) {
    float dtv = sdt[i][dl], uv = su[i][dl];
    float dtA = dtv * Aval;
    float rinv = __builtin_amdgcn_rcpf(1.f - 0.5f * dtA);
    float dA = (1.f + 0.5f * dtA) * rinv;
    float dBu = dtv * sB[i][n] * rinv * uv;
    h = dA * h + dBu;
    float p = h * sC[i][n];
    p += __shfl_xor(p, 1);
    p += __shfl_xor(p, 2);
    p += __shfl_xor(p, 4);
    p += __shfl_xor(p, 8);
    if (n == 0) {
      float rv = sres[i][dl];
      float yv = (p + uv * Dpv) * (rv / (1.f + expf(-rv)));
      y2b[(size_t)(t0 + i) * DINNER + d] = f2bf(yv);
    }
  }
}

// ---------------- unified weight preprocessing (one launch) -----------------
__global__ __launch_bounds__(256) void preproc_kernel(
    const float* __restrict__ embed, const float* __restrict__ Wres,
    const float* __restrict__ Win, const float* __restrict__ Wout,
    const float* __restrict__ WB, const float* __restrict__ WC,
    const float* __restrict__ Wdt1, const float* __restrict__ Wdt2,
    ushort* __restrict__ eb, ushort* __restrict__ wcatb,
    ushort* __restrict__ woutb, ushort* __restrict__ wbcdtb,
    ushort* __restrict__ wdt2b)
{
  const size_t S0 = (size_t)VOCAB * DMODEL / 4;
  const size_t S1 = (size_t)NLAYER * 2 * DINNER * DMODEL / 4;
  const size_t S2 = (size_t)NLAYER * DMODEL * DINNER / 4;
  const size_t S3 = (size_t)NLAYER * 128 * DINNER / 4;
  const size_t S4 = (size_t)NLAYER * DINNER * DTRANK / 4;
  size_t i4 = (size_t)blockIdx.x * 256 + threadIdx.x;
  float4 v;
  ushort* dst;
  size_t di;
  if (i4 < S0) {
    v = ((const float4*)embed)[i4];
    dst = eb; di = i4;
  } else if (i4 < S0 + S1) {
    size_t j4 = i4 - S0;
    size_t e0 = j4 * 4;
    int k = (int)(e0 & (DMODEL - 1));
    int r = (int)((e0 >> 10) & (2 * DINNER - 1));
    int l = (int)(e0 >> 22);
    const float* src = (r < DINNER)
        ? &Wres[(((size_t)l * DINNER + r) << 10) + k]
        : &Win[(((size_t)l * DINNER + (r - DINNER)) << 10) + k];
    v = *(const float4*)src;
    dst = wcatb; di = j4;
  } else if (i4 < S0 + S1 + S2) {
    size_t j4 = i4 - S0 - S1;
    v = ((const float4*)Wout)[j4];
    dst = woutb; di = j4;
  } else if (i4 < S0 + S1 + S2 + S3) {
    size_t j4 = i4 - S0 - S1 - S2;
    int k4 = (int)(j4 & (DINNER / 4 - 1));
    int row = (int)((j4 >> 9) & 127);
    int l = (int)(j4 >> 16);
    int k = k4 * 4;
    v = (float4){0.f, 0.f, 0.f, 0.f};
    if (row < 16)       v = *(const float4*)&WB[((size_t)l * DSTATE + row) * DINNER + k];
    else if (row < 32)  v = *(const float4*)&WC[((size_t)l * DSTATE + (row - 16)) * DINNER + k];
    else if (row < 96)  v = *(const float4*)&Wdt1[((size_t)l * DTRANK + (row - 32)) * DINNER + k];
    dst = wbcdtb; di = j4;
  } else if (i4 < S0 + S1 + S2 + S3 + S4) {
    size_t j4 = i4 - S0 - S1 - S2 - S3;
    v = ((const float4*)Wdt2)[j4];
    dst = wdt2b; di = j4;
  } else {
    return;
  }
  ushort4 o = {f2bf(v.x), f2bf(v.y), f2bf(v.z), f2bf(v.w)};
  ((ushort4*)dst)[di] = o;
}

// ============================================================================
extern "C" void kernel_launch(void* const* d_in, const int* in_sizes, int n_in,
                              void* d_out, int out_size, void* d_ws, size_t ws_size,
                              hipStream_t stream) {
  (void)in_sizes; (void)n_in; (void)out_size;
  const int* token_ids = (const int*)d_in[0];
  const float* embed = (const float*)d_in[1];
  const float* Wres = (const float*)d_in[2];
  const float* Win = (const float*)d_in[3];
  const float* Wconv = (const float*)d_in[4];
  const float* WB = (const float*)d_in[5];
  const float* WC = (const float*)d_in[6];
  const float* Wdt1 = (const float*)d_in[7];
  const float* Wdt2 = (const float*)d_in[8];
  const float* bdt = (const float*)d_in[9];
  const float* logA = (const float*)d_in[10];
  const float* Dp = (const float*)d_in[11];
  const float* Wout = (const float*)d_in[12];
  float* out = (float*)d_out;

  char* w = (char*)d_ws;
  auto alloc = [&](size_t bytes) {
    char* p = w;
    w += (bytes + 255) & ~(size_t)255;
    return p;
  };
  ushort* eb     = (ushort*)alloc((size_t)VOCAB * DMODEL * 2);
  ushort* wcatb  = (ushort*)alloc((size_t)NLAYER * 2 * DINNER * DMODEL * 2);
  ushort* woutb  = (ushort*)alloc((size_t)NLAYER * DMODEL * DINNER * 2);
  ushort* wbcdtb = (ushort*)alloc((size_t)NLAYER * 128 * DINNER * 2);
  ushort* wdt2b  = (ushort*)alloc((size_t)NLAYER * DINNER * DTRANK * 2);
  float* x       = (float*)alloc((size_t)SEQ * DMODEL * 4);
  ushort* xnb    = (ushort*)alloc((size_t)SEQ * DMODEL * 2);
  ushort* resu0  = (ushort*)alloc((size_t)SEQ * 2 * DINNER * 2);
  ushort* u      = (ushort*)alloc((size_t)SEQ * DINNER * 2);
  float* bcdt    = (float*)alloc((size_t)SEQ * 96 * 4);
  ushort* dtinb  = (ushort*)alloc((size_t)SEQ * 64 * 2);
  float* Cp      = (float*)alloc((size_t)PZ * SEQ * 128 * 4);
  ushort* Cp2    = (ushort*)alloc((size_t)2 * SEQ * DMODEL * 2);
  float* Pbuf    = (float*)alloc((size_t)NCHUNK * DINNER * DSTATE * 4);
  float* Sbuf    = (float*)alloc((size_t)NCHUNK * DINNER * DSTATE * 4);
  ushort* y2b    = (ushort*)alloc((size_t)SEQ * DINNER * 2);
  ushort* xb     = (ushort*)alloc((size_t)SEQ * DMODEL * 2);
  if ((size_t)(w - (char*)d_ws) > ws_size) return;

  {
    size_t total4 = (size_t)VOCAB * DMODEL / 4
                  + (size_t)NLAYER * 2 * DINNER * DMODEL / 4
                  + (size_t)NLAYER * DMODEL * DINNER / 4
                  + (size_t)NLAYER * 128 * DINNER / 4
                  + (size_t)NLAYER * DINNER * DTRANK / 4;
    int nblk = (int)((total4 + 255) / 256);
    preproc_kernel<<<nblk, 256, 0, stream>>>(
        embed, Wres, Win, Wout, WB, WC, Wdt1, Wdt2,
        eb, wcatb, woutb, wbcdtb, wdt2b);
  }
  gather_rms_kernel<<<SEQ, 256, 0, stream>>>(token_ids, embed, x, xnb);

  for (int i = 0; i < NLAYER; ++i) {
    const ushort* wcati = wcatb + (size_t)i * 2 * DINNER * DMODEL;
    const ushort* wouti = woutb + (size_t)i * DMODEL * DINNER;
    const float* wconvi = Wconv + (size_t)i * DINNER * 4;
    const ushort* wbcdtbi = wbcdtb + (size_t)i * 128 * DINNER;
    const ushort* wdt2bi = wdt2b + (size_t)i * DINNER * DTRANK;
    const float* bdti = bdt + (size_t)i * DINNER;
    const float* logAi = logA + (size_t)i * DINNER * DSTATE;
    const float* Dpi = Dp + (size_t)i * DINNER;

    gemm2p_bt_bf16<true><<<dim3(SEQ / 128, 2 * DINNER / 128), 256, 0, stream>>>(
        xnb, wcati, resu0, 2 * DINNER, DMODEL);
    convproj_mfma<<<dim3(SEQ / 128, 1, PZ), 256, 0, stream>>>(
        resu0, wbcdtbi, wconvi, u, Cp, SEQ);
    proj_reduce<<<SEQ * 96 / 256, 256, 0, stream>>>(Cp, bcdt, dtinb, SEQ);
    dim3 gs(DINNER / 16, NCHUNK);
    scan_pass1<<<gs, 256, 0, stream>>>(dtinb, u, bcdt, wdt2bi, bdti, logAi, Pbuf, Sbuf);
    scan_pass2<<<gs, 256, 0, stream>>>(dtinb, u, bcdt, wdt2bi, bdti, logAi, Dpi,
                                       Pbuf, Sbuf, resu0, y2b);
    gemm_btk_bf16<<<dim3(SEQ / 128, DMODEL / 128, 2), 256, 0, stream>>>(
        y2b, wouti, Cp2, SEQ, DMODEL, DINNER);
    add3_rms_kernel<<<SEQ, 256, 0, stream>>>(
        Cp2, Cp2 + (size_t)SEQ * DMODEL, x,
        (i < NLAYER - 1) ? xnb : xb, (i < NLAYER - 1) ? 1 : 0);
  }
  gemm8p_bt_bf16<256, true><<<dim3(SEQ / 256, VOCAB / 256), 512, 0, stream>>>(
      xb, eb, out, VOCAB, DMODEL);
}

// Round 21
// 1911.576 us; speedup vs baseline: 1.0391x; 1.0391x over previous
//
#include <hip/hip_runtime.h>

#define SEQ 2048
#define DMODEL 1024
#define DINNER 2048
#define DSTATE 16
#define DTRANK 64
#define NLAYER 8
#define VOCAB 32000
#define NCHUNK 32
#define CLEN 64   // SEQ / NCHUNK
#define PZ 16     // split-K chunks for the projection GEMM

typedef float f32x4 __attribute__((ext_vector_type(4)));
typedef short bf16x8 __attribute__((ext_vector_type(8)));

__device__ __forceinline__ ushort f2bf(float f) {
  union { float f; unsigned u; } v; v.f = f;
  unsigned r = v.u + 0x7fffu + ((v.u >> 16) & 1u);
  return (ushort)(r >> 16);
}
__device__ __forceinline__ float bf2f(ushort b) {
  union { unsigned u; float f; } v; v.u = ((unsigned)b) << 16;
  return v.f;
}

__device__ __forceinline__ void lds_load16(const void* g, void* l) {
  __builtin_amdgcn_global_load_lds(
      (const __attribute__((address_space(1))) void*)g,
      (__attribute__((address_space(3))) void*)l, 16, 0, 0);
}

// ---------------- 256x256 counted-vmcnt MFMA GEMM (proven ~197us logits) ----
template<int BM, bool NTS>
__global__ __launch_bounds__(512, 2) void gemm8p_bt_bf16(
    const ushort* __restrict__ A, const ushort* __restrict__ B,
    float* __restrict__ C, int N, int K)
{
  constexpr int MFR = BM / 32;
  constexpr int MPP = MFR / 4;
  constexpr int ALOADS = BM / 128;
  __shared__ __align__(16) ushort As[2 * BM * 64];
  __shared__ __align__(16) ushort Bs[2 * 256 * 64];
  const int tid = threadIdx.x;
  const int lane = tid & 63;
  const int wid = tid >> 6;
  const int wr = wid >> 2, wc = wid & 3;
  const int rr = lane & 15, kq = lane >> 4;

  unsigned nwg = gridDim.x * gridDim.y;
  unsigned lb = blockIdx.y * gridDim.x + blockIdx.x;
  if ((nwg & 7u) == 0u) { unsigned cpx = nwg >> 3; lb = (lb & 7u) * cpx + (lb >> 3); }
  const int bm = (int)(lb % gridDim.x) * BM;
  const int bn = (int)(lb / gridDim.x) * 256;

  const ushort* Abase = A + (size_t)bm * K;
  const ushort* Bbase = B + (size_t)bn * K;

  auto stageA = [&](int buf, int h, int kt) {
    constexpr int HR = BM / 2;
#pragma unroll
    for (int L = 0; L < ALOADS; ++L) {
      int f = L * 512 + tid;
      int rl = f >> 3, g = f & 7;
      int gg = g ^ (rl & 7);
      lds_load16(Abase + (size_t)(h * HR + rl) * K + kt * 64 + gg * 8,
                 (void*)(As + buf * (BM * 64) + (h * HR + rl) * 64 + g * 8));
    }
  };
  auto stageB = [&](int buf, int h, int kt) {
#pragma unroll
    for (int L = 0; L < 2; ++L) {
      int f = L * 512 + tid;
      int rl = f >> 3, g = f & 7;
      int gg = g ^ (rl & 7);
      lds_load16(Bbase + (size_t)(h * 128 + rl) * K + kt * 64 + gg * 8,
                 (void*)(Bs + buf * (256 * 64) + (h * 128 + rl) * 64 + g * 8));
    }
  };
  auto rdA = [&](int buf, int r, int kbyte) {
    int sw = kbyte ^ ((r & 7) << 4);
    return *(const bf16x8*)(As + buf * (BM * 64) + r * 64 + (sw >> 1));
  };
  auto rdB = [&](int buf, int r, int kbyte) {
    int sw = kbyte ^ ((r & 7) << 4);
    return *(const bf16x8*)(Bs + buf * (256 * 64) + r * 64 + (sw >> 1));
  };

  f32x4 acc[MFR][4];
#pragma unroll
  for (int m = 0; m < MFR; ++m)
#pragma unroll
    for (int n = 0; n < 4; ++n) acc[m][n] = (f32x4){0.f, 0.f, 0.f, 0.f};

  const int NT = K >> 6;
  stageA(0, 0, 0); stageA(0, 1, 0); stageB(0, 0, 0); stageB(0, 1, 0);

  for (int t = 0; t < NT; ++t) {
    const int cur = t & 1;
    const bool more = (t + 1 < NT);
    if (more) stageA(cur ^ 1, 0, t + 1);
    if (more) {
      if constexpr (BM == 256) asm volatile("s_waitcnt vmcnt(2)" ::: "memory");
      else                     asm volatile("s_waitcnt vmcnt(1)" ::: "memory");
    } else {
      asm volatile("s_waitcnt vmcnt(0)" ::: "memory");
    }
    __syncthreads();

    bf16x8 bfr[4][2];
#pragma unroll
    for (int n = 0; n < 4; ++n)
#pragma unroll
      for (int kk = 0; kk < 2; ++kk)
        bfr[n][kk] = rdB(cur, wc * 64 + n * 16 + rr, kk * 64 + kq * 16);

#pragma unroll
    for (int mq = 0; mq < 4; ++mq) {
      if (mq == 1 && more) stageA(cur ^ 1, 1, t + 1);
      if (mq == 2 && more) stageB(cur ^ 1, 0, t + 1);
      if (mq == 3 && more) stageB(cur ^ 1, 1, t + 1);
      bf16x8 af[MPP][2];
#pragma unroll
      for (int mf = 0; mf < MPP; ++mf)
#pragma unroll
        for (int kk = 0; kk < 2; ++kk)
          af[mf][kk] = rdA(cur, wr * (BM / 2) + (mq * MPP + mf) * 16 + rr, kk * 64 + kq * 16);
      __builtin_amdgcn_s_setprio(1);
#pragma unroll
      for (int kk = 0; kk < 2; ++kk)
#pragma unroll
        for (int mf = 0; mf < MPP; ++mf)
#pragma unroll
          for (int n = 0; n < 4; ++n)
            acc[mq * MPP + mf][n] = __builtin_amdgcn_mfma_f32_16x16x32_bf16(
                af[mf][kk], bfr[n][kk], acc[mq * MPP + mf][n], 0, 0, 0);
      __builtin_amdgcn_s_setprio(0);
    }
    __syncthreads();
  }

  float* ep = (float*)Bs + wid * (16 * 68);
  const int cg = bn + wc * 64;
#pragma unroll
  for (int m = 0; m < MFR; ++m) {
    const int r0g = bm + wr * (BM / 2) + m * 16;
#pragma unroll
    for (int n = 0; n < 4; ++n)
#pragma unroll
      for (int j = 0; j < 4; ++j)
        ep[(kq * 4 + j) * 68 + n * 16 + rr] = acc[m][n][j];
#pragma unroll
    for (int i = 0; i < 4; ++i) {
      int row = i * 4 + kq;
      f32x4 v = *(const f32x4*)&ep[row * 68 + rr * 4];
      f32x4* dst = (f32x4*)&C[(size_t)(r0g + row) * N + cg + rr * 4];
      if constexpr (NTS) __builtin_nontemporal_store(v, dst);
      else *dst = v;
    }
  }
}

// ---------------- 128x128 2-blocks/CU MFMA GEMM (layer gemm1) ---------------
template<bool OUTBF>
__global__ __launch_bounds__(256, 2) void gemm2p_bt_bf16(
    const ushort* __restrict__ A, const ushort* __restrict__ B,
    void* __restrict__ Cv, int N, int K)
{
  __shared__ __align__(16) ushort As[2 * 128 * 64];
  __shared__ __align__(16) ushort Bs[2 * 128 * 64];
  const int tid = threadIdx.x;
  const int lane = tid & 63;
  const int wave = tid >> 6;
  const int wr = wave >> 1, wc = wave & 1;
  const int rr = lane & 15, kq = lane >> 4;

  unsigned nwg = gridDim.x * gridDim.y;
  unsigned lb = blockIdx.y * gridDim.x + blockIdx.x;
  if ((nwg & 7u) == 0u) { unsigned cpx = nwg >> 3; lb = (lb & 7u) * cpx + (lb >> 3); }
  const int bm = (int)(lb % gridDim.x) * 128;
  const int bn = (int)(lb / gridDim.x) * 128;

  const ushort* Abase = A + (size_t)bm * K;
  const ushort* Bbase = B + (size_t)bn * K;

  auto stage = [&](int buf, int kt) {
#pragma unroll
    for (int i = 0; i < 4; ++i) {
      int f = i * 256 + tid;
      int rl = f >> 3, g = f & 7;
      int gg = g ^ (rl & 7);
      lds_load16(Abase + (size_t)rl * K + kt * 64 + gg * 8,
                 (void*)(As + buf * 8192 + rl * 64 + g * 8));
      lds_load16(Bbase + (size_t)rl * K + kt * 64 + gg * 8,
                 (void*)(Bs + buf * 8192 + rl * 64 + g * 8));
    }
  };
  auto rdA = [&](int buf, int r, int kbyte) {
    int sw = kbyte ^ ((r & 7) << 4);
    return *(const bf16x8*)(As + buf * 8192 + r * 64 + (sw >> 1));
  };
  auto rdB = [&](int buf, int r, int kbyte) {
    int sw = kbyte ^ ((r & 7) << 4);
    return *(const bf16x8*)(Bs + buf * 8192 + r * 64 + (sw >> 1));
  };

  f32x4 acc[4][4];
#pragma unroll
  for (int m = 0; m < 4; ++m)
#pragma unroll
    for (int n = 0; n < 4; ++n) acc[m][n] = (f32x4){0.f, 0.f, 0.f, 0.f};

  const int NT = K >> 6;
  stage(0, 0);

  for (int t = 0; t < NT; ++t) {
    const int cur = t & 1;
    if (t + 1 < NT) {
      stage(cur ^ 1, t + 1);
      asm volatile("s_waitcnt vmcnt(8)" ::: "memory");
    } else {
      asm volatile("s_waitcnt vmcnt(0)" ::: "memory");
    }
    __syncthreads();
#pragma unroll
    for (int ks = 0; ks < 2; ++ks) {
      const int kbyte = ks * 64 + kq * 16;
      bf16x8 af[4], bfr[4];
#pragma unroll
      for (int m = 0; m < 4; ++m)
        af[m] = rdA(cur, wr * 64 + m * 16 + rr, kbyte);
#pragma unroll
      for (int n = 0; n < 4; ++n)
        bfr[n] = rdB(cur, wc * 64 + n * 16 + rr, kbyte);
      __builtin_amdgcn_s_setprio(1);
#pragma unroll
      for (int m = 0; m < 4; ++m)
#pragma unroll
        for (int n = 0; n < 4; ++n)
          acc[m][n] = __builtin_amdgcn_mfma_f32_16x16x32_bf16(af[m], bfr[n], acc[m][n], 0, 0, 0);
      __builtin_amdgcn_s_setprio(0);
    }
    __syncthreads();
  }

  float* ep = (float*)Bs + wave * (16 * 68);
  const int cg = bn + wc * 64;
#pragma unroll
  for (int m = 0; m < 4; ++m) {
    const int r0g = bm + wr * 64 + m * 16;
#pragma unroll
    for (int n = 0; n < 4; ++n)
#pragma unroll
      for (int j = 0; j < 4; ++j)
        ep[(kq * 4 + j) * 68 + n * 16 + rr] = acc[m][n][j];
#pragma unroll
    for (int i = 0; i < 4; ++i) {
      int row = i * 4 + kq;
      f32x4 v = *(const f32x4*)&ep[row * 68 + rr * 4];
      if constexpr (OUTBF) {
        ushort* C = (ushort*)Cv;
        ushort4 o = {f2bf(v.x), f2bf(v.y), f2bf(v.z), f2bf(v.w)};
        *(ushort4*)&C[(size_t)(r0g + row) * N + cg + rr * 4] = o;
      } else {
        float* C = (float*)Cv;
        *(f32x4*)&C[(size_t)(r0g + row) * N + cg + rr * 4] = v;
      }
    }
  }
}

// ---- split-K bf16 MFMA GEMM (2-phase 128x128, T2 swizzle, bf16 partials) ---
__global__ __launch_bounds__(256) void gemm_btk_bf16(
    const ushort* __restrict__ A, const ushort* __restrict__ B,
    ushort* __restrict__ Cp, int M, int N, int K)
{
  __shared__ __align__(16) ushort As[128 * 64];
  __shared__ __align__(16) ushort Bs[128 * 64];
  const int tid = threadIdx.x;
  const int lane = tid & 63;
  const int wave = tid >> 6;
  const int wr = wave >> 1, wc = wave & 1;
  const int KC = K / gridDim.z;
  const int k0 = blockIdx.z * KC;

  unsigned nwg = gridDim.x * gridDim.y;
  unsigned lb = blockIdx.y * gridDim.x + blockIdx.x;
  if ((nwg & 7u) == 0u) {
    unsigned cpx = nwg >> 3;
    lb = (lb & 7u) * cpx + (lb >> 3);
  }
  const int bm = (lb % gridDim.x) * 128;
  const int bn = (lb / gridDim.x) * 128;
  const int rr = lane & 15, kq = lane >> 4;

  auto rdA = [&](int r, int kbyte) {
    int sw = kbyte ^ ((r & 7) << 4);
    return *(const bf16x8*)(As + r * 64 + (sw >> 1));
  };
  auto rdB = [&](int r, int kbyte) {
    int sw = kbyte ^ ((r & 7) << 4);
    return *(const bf16x8*)(Bs + r * 64 + (sw >> 1));
  };

  f32x4 acc[4][4];
#pragma unroll
  for (int m = 0; m < 4; ++m)
#pragma unroll
    for (int n = 0; n < 4; ++n) acc[m][n] = (f32x4){0.f, 0.f, 0.f, 0.f};

  for (int kt = 0; kt < KC; kt += 64) {
#pragma unroll
    for (int i = 0; i < 4; ++i) {
      int fb = i * 256 + tid;
      int row = fb >> 3, g = fb & 7;
      int gg = g ^ (row & 7);
      lds_load16(A + (size_t)(bm + row) * K + k0 + kt + gg * 8, (void*)(As + (size_t)fb * 8));
      lds_load16(B + (size_t)(bn + row) * K + k0 + kt + gg * 8, (void*)(Bs + (size_t)fb * 8));
    }
    asm volatile("s_waitcnt vmcnt(0)" ::: "memory");
    __syncthreads();
#pragma unroll
    for (int ks = 0; ks < 2; ++ks) {
      const int kbyte = ks * 64 + kq * 16;
      bf16x8 af[4], bfr[4];
#pragma unroll
      for (int m = 0; m < 4; ++m)
        af[m] = rdA(wr * 64 + m * 16 + rr, kbyte);
#pragma unroll
      for (int n = 0; n < 4; ++n)
        bfr[n] = rdB(wc * 64 + n * 16 + rr, kbyte);
#pragma unroll
      for (int m = 0; m < 4; ++m)
#pragma unroll
        for (int n = 0; n < 4; ++n)
          acc[m][n] = __builtin_amdgcn_mfma_f32_16x16x32_bf16(af[m], bfr[n], acc[m][n], 0, 0, 0);
    }
    __syncthreads();
  }
  ushort* C = Cp + (size_t)blockIdx.z * M * N;
#pragma unroll
  for (int m = 0; m < 4; ++m) {
    const int r0 = bm + wr * 64 + m * 16 + kq * 4;
#pragma unroll
    for (int n = 0; n < 4; ++n) {
      const int cc = bn + wc * 64 + n * 16 + rr;
#pragma unroll
      for (int j = 0; j < 4; ++j)
        C[(size_t)(r0 + j) * N + cc] = f2bf(acc[m][n][j]);
    }
  }
}

// ---------------- fused conv+SiLU + split-K MFMA projection (T2 swizzle) ----
__global__ __launch_bounds__(256) void convproj_mfma(
    const ushort* __restrict__ resu0, const ushort* __restrict__ W,
    const float* __restrict__ Wconv, ushort* __restrict__ u,
    float* __restrict__ Cp, int M)
{
  __shared__ __align__(16) ushort u0s[131][128];
  __shared__ __align__(16) ushort As[2][128 * 64];
  __shared__ __align__(16) ushort Bs[2][128 * 64];
  const int tid = threadIdx.x;
  const int lane = tid & 63;
  const int wave = tid >> 6;
  const int wr = wave >> 1, wc = wave & 1;
  const int rr = lane & 15, kq = lane >> 4;
  const int bm = blockIdx.x * 128;
  const int kc = blockIdx.z * 128;

#pragma unroll
  for (int h = 0; h < 2; ++h)
#pragma unroll
    for (int i = 0; i < 4; ++i) {
      int f = i * 256 + tid;
      int rl = f >> 3, g = f & 7;
      int gg = g ^ (rl & 7);
      lds_load16(W + (size_t)rl * DINNER + kc + h * 64 + gg * 8,
                 (void*)(&Bs[h][rl * 64 + g * 8]));
    }

  for (int i = tid; i < 131 * 32; i += 256) {
    int row = i >> 5, c4 = (i & 31) * 4;
    int gr = bm - 3 + row;
    ushort4 v = {0, 0, 0, 0};
    if (gr >= 0)
      v = *(const ushort4*)&resu0[(size_t)gr * (2 * DINNER) + DINNER + kc + c4];
    *(ushort4*)&u0s[row][c4] = v;
  }
  __syncthreads();

  {
    const int c0 = (tid & 31) * 4;
    const int r0 = (tid >> 5) * 16;
    float4 w0 = *(const float4*)&Wconv[(kc + c0 + 0) * 4];
    float4 w1 = *(const float4*)&Wconv[(kc + c0 + 1) * 4];
    float4 w2 = *(const float4*)&Wconv[(kc + c0 + 2) * 4];
    float4 w3 = *(const float4*)&Wconv[(kc + c0 + 3) * 4];
    const int ks = c0 >> 6;
    const int cl = c0 & 63;
    for (int r = r0; r < r0 + 16; ++r) {
      ushort4 a0 = *(const ushort4*)&u0s[r + 0][c0];
      ushort4 a1 = *(const ushort4*)&u0s[r + 1][c0];
      ushort4 a2 = *(const ushort4*)&u0s[r + 2][c0];
      ushort4 a3 = *(const ushort4*)&u0s[r + 3][c0];
      float o0 = bf2f(a0.x) * w0.x + bf2f(a1.x) * w0.y + bf2f(a2.x) * w0.z + bf2f(a3.x) * w0.w;
      float o1 = bf2f(a0.y) * w1.x + bf2f(a1.y) * w1.y + bf2f(a2.y) * w1.z + bf2f(a3.y) * w1.w;
      float o2 = bf2f(a0.z) * w2.x + bf2f(a1.z) * w2.y + bf2f(a2.z) * w2.z + bf2f(a3.z) * w2.w;
      float o3 = bf2f(a0.w) * w3.x + bf2f(a1.w) * w3.y + bf2f(a2.w) * w3.z + bf2f(a3.w) * w3.w;
      o0 = o0 / (1.f + expf(-o0));
      o1 = o1 / (1.f + expf(-o1));
      o2 = o2 / (1.f + expf(-o2));
      o3 = o3 / (1.f + expf(-o3));
      ushort4 o = {f2bf(o0), f2bf(o1), f2bf(o2), f2bf(o3)};
      int sg = ((cl >> 3) ^ (r & 7)) * 8 + (cl & 7);
      *(ushort4*)&As[ks][r * 64 + sg] = o;
      *(ushort4*)&u[(size_t)(bm + r) * DINNER + kc + c0] = o;
    }
  }
  asm volatile("s_waitcnt vmcnt(0)" ::: "memory");
  __syncthreads();

  f32x4 acc[4][4];
#pragma unroll
  for (int m = 0; m < 4; ++m)
#pragma unroll
    for (int n = 0; n < 4; ++n) acc[m][n] = (f32x4){0.f, 0.f, 0.f, 0.f};

#pragma unroll
  for (int ks = 0; ks < 2; ++ks) {
#pragma unroll
    for (int kk = 0; kk < 2; ++kk) {
      const int kbyte = kk * 64 + kq * 16;
      bf16x8 af[4], bfr[4];
#pragma unroll
      for (int m = 0; m < 4; ++m) {
        int r = wr * 64 + m * 16 + rr;
        int sw = kbyte ^ ((r & 7) << 4);
        af[m] = *(const bf16x8*)&As[ks][r * 64 + (sw >> 1)];
      }
#pragma unroll
      for (int n = 0; n < 4; ++n) {
        int r = wc * 64 + n * 16 + rr;
        int sw = kbyte ^ ((r & 7) << 4);
        bfr[n] = *(const bf16x8*)&Bs[ks][r * 64 + (sw >> 1)];
      }
      __builtin_amdgcn_s_setprio(1);
#pragma unroll
      for (int m = 0; m < 4; ++m)
#pragma unroll
        for (int n = 0; n < 4; ++n)
          acc[m][n] = __builtin_amdgcn_mfma_f32_16x16x32_bf16(af[m], bfr[n], acc[m][n], 0, 0, 0);
      __builtin_amdgcn_s_setprio(0);
    }
  }

  float* C = Cp + (size_t)blockIdx.z * M * 128;
#pragma unroll
  for (int m = 0; m < 4; ++m) {
    const int r0 = bm + wr * 64 + m * 16 + kq * 4;
#pragma unroll
    for (int n = 0; n < 4; ++n) {
      const int cc = wc * 64 + n * 16 + rr;
#pragma unroll
      for (int j = 0; j < 4; ++j)
        C[(size_t)(r0 + j) * 128 + cc] = acc[m][n][j];
    }
  }
}

// ---------------- dt GEMM (K=64, bf16 dtin input, T2 swizzle) ---------------
__global__ __launch_bounds__(256) void gemm_dt_bf16(
    const ushort* __restrict__ A, const ushort* __restrict__ W,
    const float* __restrict__ bias, ushort* __restrict__ dt)
{
  __shared__ __align__(16) ushort As[128 * 64];
  __shared__ __align__(16) ushort Bs[128 * 64];
  __shared__ float eps[4 * 16 * 68];
  const int tid = threadIdx.x;
  const int lane = tid & 63;
  const int wave = tid >> 6;
  const int wr = wave >> 1, wc = wave & 1;
  const int rr = lane & 15, kq = lane >> 4;
  const int bm = blockIdx.x * 128;
  const int bn = blockIdx.y * 128;

#pragma unroll
  for (int i = 0; i < 4; ++i) {
    int f = i * 256 + tid;
    int rl = f >> 3, g = f & 7;
    int gg = g ^ (rl & 7);
    lds_load16(A + (size_t)(bm + rl) * DTRANK + gg * 8, (void*)(As + (size_t)f * 8));
    lds_load16(W + (size_t)(bn + rl) * DTRANK + gg * 8, (void*)(Bs + (size_t)f * 8));
  }
  asm volatile("s_waitcnt vmcnt(0)" ::: "memory");
  __syncthreads();

  f32x4 acc[4][4];
#pragma unroll
  for (int m = 0; m < 4; ++m)
#pragma unroll
    for (int n = 0; n < 4; ++n) acc[m][n] = (f32x4){0.f, 0.f, 0.f, 0.f};

#pragma unroll
  for (int ks = 0; ks < 2; ++ks) {
    const int kbyte = ks * 64 + kq * 16;
    bf16x8 af[4], bfr[4];
#pragma unroll
    for (int m = 0; m < 4; ++m) {
      int r = wr * 64 + m * 16 + rr;
      int sw = kbyte ^ ((r & 7) << 4);
      af[m] = *(const bf16x8*)&As[r * 64 + (sw >> 1)];
    }
#pragma unroll
    for (int n = 0; n < 4; ++n) {
      int r = wc * 64 + n * 16 + rr;
      int sw = kbyte ^ ((r & 7) << 4);
      bfr[n] = *(const bf16x8*)&Bs[r * 64 + (sw >> 1)];
    }
#pragma unroll
    for (int m = 0; m < 4; ++m)
#pragma unroll
      for (int n = 0; n < 4; ++n)
        acc[m][n] = __builtin_amdgcn_mfma_f32_16x16x32_bf16(af[m], bfr[n], acc[m][n], 0, 0, 0);
  }
  __syncthreads();

  float* ep = eps + wave * (16 * 68);
  const int cgb = bn + wc * 64 + rr * 4;
  float4 b4 = *(const float4*)&bias[cgb];
#pragma unroll
  for (int m = 0; m < 4; ++m) {
    const int r0g = bm + wr * 64 + m * 16;
#pragma unroll
    for (int n = 0; n < 4; ++n)
#pragma unroll
      for (int j = 0; j < 4; ++j)
        ep[(kq * 4 + j) * 68 + n * 16 + rr] = acc[m][n][j];
#pragma unroll
    for (int i = 0; i < 4; ++i) {
      int row = i * 4 + kq;
      f32x4 v = *(const f32x4*)&ep[row * 68 + rr * 4];
      float v0 = v.x + b4.x, v1 = v.y + b4.y, v2 = v.z + b4.z, v3 = v.w + b4.w;
      v0 = (v0 > 20.f) ? v0 : log1pf(expf(v0));
      v1 = (v1 > 20.f) ? v1 : log1pf(expf(v1));
      v2 = (v2 > 20.f) ? v2 : log1pf(expf(v2));
      v3 = (v3 > 20.f) ? v3 : log1pf(expf(v3));
      ushort4 o = {f2bf(v0), f2bf(v1), f2bf(v2), f2bf(v3)};
      *(ushort4*)&dt[(size_t)(r0g + row) * DINNER + cgb] = o;
    }
  }
}

// ---- x += P0 + P1 (bf16 partials), then RMSNorm(x)->bf16 (or plain cast) ---
__global__ __launch_bounds__(256) void add3_rms_kernel(
    const ushort* __restrict__ P0, const ushort* __restrict__ P1,
    float* __restrict__ x, ushort* __restrict__ dst, int donorm)
{
  size_t o = (size_t)blockIdx.x * (DMODEL / 4) + threadIdx.x;
  ushort4 a = ((const ushort4*)P0)[o];
  ushort4 b = ((const ushort4*)P1)[o];
  float4 c = ((float4*)x)[o];
  c.x += bf2f(a.x) + bf2f(b.x);
  c.y += bf2f(a.y) + bf2f(b.y);
  c.z += bf2f(a.z) + bf2f(b.z);
  c.w += bf2f(a.w) + bf2f(b.w);
  ((float4*)x)[o] = c;
  float sc = 1.f;
  if (donorm) {
    float s = c.x * c.x + c.y * c.y + c.z * c.z + c.w * c.w;
#pragma unroll
    for (int off = 32; off > 0; off >>= 1) s += __shfl_down(s, off);
    __shared__ float ws[4];
    if ((threadIdx.x & 63) == 0) ws[threadIdx.x >> 6] = s;
    __syncthreads();
    float tot = ws[0] + ws[1] + ws[2] + ws[3];
    sc = rsqrtf(tot * (1.0f / DMODEL) + 1e-6f);
  }
  ushort4 o4 = {f2bf(c.x * sc), f2bf(c.y * sc), f2bf(c.z * sc), f2bf(c.w * sc)};
  ((ushort4*)dst)[o] = o4;
}

// ---------------- embedding gather + RMSNorm -> x (f32) and xnb (bf16) ------
__global__ __launch_bounds__(256) void gather_rms_kernel(
    const int* __restrict__ ids, const float* __restrict__ embed,
    float* __restrict__ x, ushort* __restrict__ xnb)
{
  int row = blockIdx.x;
  int id = ids[row];
  float4 v = ((const float4*)(embed + (size_t)id * DMODEL))[threadIdx.x];
  size_t o = (size_t)row * (DMODEL / 4) + threadIdx.x;
  ((float4*)x)[o] = v;
  float s = v.x * v.x + v.y * v.y + v.z * v.z + v.w * v.w;
#pragma unroll
  for (int off = 32; off > 0; off >>= 1) s += __shfl_down(s, off);
  __shared__ float ws[4];
  if ((threadIdx.x & 63) == 0) ws[threadIdx.x >> 6] = s;
  __syncthreads();
  float tot = ws[0] + ws[1] + ws[2] + ws[3];
  float sc = rsqrtf(tot * (1.0f / DMODEL) + 1e-6f);
  ushort4 o4 = {f2bf(v.x * sc), f2bf(v.y * sc), f2bf(v.z * sc), f2bf(v.w * sc)};
  ((ushort4*)xnb)[o] = o4;
}

// ---- proj reduce: B/C -> bcdt f32 (cols 0..31), dt-in -> dtinb bf16 --------
__global__ __launch_bounds__(256) void proj_reduce(
    const float* __restrict__ Cp, float* __restrict__ bcdt,
    ushort* __restrict__ dtinb, int M)
{
  int idx = blockIdx.x * 256 + threadIdx.x;
  int row = idx / 96, col = idx - row * 96;
  float s = 0.f;
#pragma unroll
  for (int c = 0; c < PZ; ++c) s += Cp[(size_t)c * M * 128 + (size_t)row * 128 + col];
  if (col < 32) bcdt[(size_t)row * 96 + col] = s;
  else dtinb[(size_t)row * 64 + (col - 32)] = f2bf(s);
}

// ---------------- chunk-parallel selective scan (bf16 dt/u inputs) ----------
__global__ __launch_bounds__(256) void scan_pass1(
    const ushort* __restrict__ dt, const ushort* __restrict__ u,
    const float* __restrict__ bcdt, const float* __restrict__ logA,
    float* __restrict__ P, float* __restrict__ S)
{
  const int tid = threadIdx.x;
  const int n = tid & 15, dl = tid >> 4;
  const int dbase = blockIdx.x * 16;
  const int c = blockIdx.y;
  const int t0 = c * CLEN;
  const int d = dbase + dl;
  const float Aval = -expf(logA[d * DSTATE + n]);
  __shared__ float sdt[CLEN][16], su[CLEN][16], sB[CLEN][16];
  {
    int tt = tid >> 2, j0 = (tid & 3) * 4;
    ushort4 rd = *(const ushort4*)&dt[(size_t)(t0 + tt) * DINNER + dbase + j0];
    ushort4 ru = *(const ushort4*)&u[(size_t)(t0 + tt) * DINNER + dbase + j0];
    sdt[tt][j0 + 0] = bf2f(rd.x); sdt[tt][j0 + 1] = bf2f(rd.y);
    sdt[tt][j0 + 2] = bf2f(rd.z); sdt[tt][j0 + 3] = bf2f(rd.w);
    su[tt][j0 + 0] = bf2f(ru.x); su[tt][j0 + 1] = bf2f(ru.y);
    su[tt][j0 + 2] = bf2f(ru.z); su[tt][j0 + 3] = bf2f(ru.w);
    *(float4*)&sB[tt][j0] = *(const float4*)&bcdt[(size_t)(t0 + tt) * 96 + j0];
  }
  __syncthreads();
  float h = 0.f, pr = 1.f;
#pragma unroll 8
  for (int i = 0; i < CLEN; ++i) {
    float dtv = sdt[i][dl], uv = su[i][dl], Bv = sB[i][n];
    float dtA = dtv * Aval;
    float rinv = __builtin_amdgcn_rcpf(1.f - 0.5f * dtA);
    float dA = (1.f + 0.5f * dtA) * rinv;
    float dBu = dtv * Bv * rinv * uv;
    h = dA * h + dBu;
    pr *= dA;
  }
  size_t idx = (size_t)c * (DINNER * DSTATE) + (size_t)d * DSTATE + n;
  P[idx] = pr;
  S[idx] = h;
}

__global__ __launch_bounds__(256) void scan_pass2(
    const ushort* __restrict__ dt, const ushort* __restrict__ u,
    const float* __restrict__ bcdt, const float* __restrict__ logA,
    const float* __restrict__ Dp, const float* __restrict__ P,
    const float* __restrict__ S, const ushort* __restrict__ resu0,
    ushort* __restrict__ y2b)
{
  const int tid = threadIdx.x;
  const int n = tid & 15, dl = tid >> 4;
  const int dbase = blockIdx.x * 16;
  const int c = blockIdx.y;
  const int t0 = c * CLEN;
  const int d = dbase + dl;
  const float Aval = -expf(logA[d * DSTATE + n]);
  const float Dpv = Dp[d];
  __shared__ float sdt[CLEN][16], su[CLEN][16], sB[CLEN][16], sC[CLEN][16], sres[CLEN][16];
  {
    int tt = tid >> 2, j0 = (tid & 3) * 4;
    ushort4 rd = *(const ushort4*)&dt[(size_t)(t0 + tt) * DINNER + dbase + j0];
    ushort4 ru = *(const ushort4*)&u[(size_t)(t0 + tt) * DINNER + dbase + j0];
    ushort4 rr4 = *(const ushort4*)&resu0[(size_t)(t0 + tt) * (2 * DINNER) + dbase + j0];
    sdt[tt][j0 + 0] = bf2f(rd.x); sdt[tt][j0 + 1] = bf2f(rd.y);
    sdt[tt][j0 + 2] = bf2f(rd.z); sdt[tt][j0 + 3] = bf2f(rd.w);
    su[tt][j0 + 0] = bf2f(ru.x); su[tt][j0 + 1] = bf2f(ru.y);
    su[tt][j0 + 2] = bf2f(ru.z); su[tt][j0 + 3] = bf2f(ru.w);
    sres[tt][j0 + 0] = bf2f(rr4.x); sres[tt][j0 + 1] = bf2f(rr4.y);
    sres[tt][j0 + 2] = bf2f(rr4.z); sres[tt][j0 + 3] = bf2f(rr4.w);
    *(float4*)&sB[tt][j0] = *(const float4*)&bcdt[(size_t)(t0 + tt) * 96 + j0];
    *(float4*)&sC[tt][j0] = *(const float4*)&bcdt[(size_t)(t0 + tt) * 96 + 16 + j0];
  }
  float h = 0.f;
  {
    const size_t base = (size_t)d * DSTATE + n;
#pragma unroll 4
    for (int cc = 0; cc < c; ++cc) {
      size_t o = (size_t)cc * (DINNER * DSTATE) + base;
      h = P[o] * h + S[o];
    }
  }
  __syncthreads();
#pragma unroll 4
  for (int i = 0; i < CLEN; ++i) {
    float dtv = sdt[i][dl], uv = su[i][dl];
    float dtA = dtv * Aval;
    float rinv = __builtin_amdgcn_rcpf(1.f - 0.5f * dtA);
    float dA = (1.f + 0.5f * dtA) * rinv;
    float dBu = dtv * sB[i][n] * rinv * uv;
    h = dA * h + dBu;
    float p = h * sC[i][n];
    p += __shfl_xor(p, 1);
    p += __shfl_xor(p, 2);
    p += __shfl_xor(p, 4);
    p += __shfl_xor(p, 8);
    if (n == 0) {
      float rv = sres[i][dl];
      float yv = (p + uv * Dpv) * (rv / (1.f + expf(-rv)));
      y2b[(size_t)(t0 + i) * DINNER + d] = f2bf(yv);
    }
  }
}

// ---------------- unified weight preprocessing (one launch) -----------------
__global__ __launch_bounds__(256) void preproc_kernel(
    const float* __restrict__ embed, const float* __restrict__ Wres,
    const float* __restrict__ Win, const float* __restrict__ Wout,
    const float* __restrict__ WB, const float* __restrict__ WC,
    const float* __restrict__ Wdt1, const float* __restrict__ Wdt2,
    ushort* __restrict__ eb, ushort* __restrict__ wcatb,
    ushort* __restrict__ woutb, ushort* __restrict__ wbcdtb,
    ushort* __restrict__ wdt2b)
{
  const size_t S0 = (size_t)VOCAB * DMODEL / 4;
  const size_t S1 = (size_t)NLAYER * 2 * DINNER * DMODEL / 4;
  const size_t S2 = (size_t)NLAYER * DMODEL * DINNER / 4;
  const size_t S3 = (size_t)NLAYER * 128 * DINNER / 4;
  const size_t S4 = (size_t)NLAYER * DINNER * DTRANK / 4;
  size_t i4 = (size_t)blockIdx.x * 256 + threadIdx.x;
  float4 v;
  ushort* dst;
  size_t di;
  if (i4 < S0) {
    v = ((const float4*)embed)[i4];
    dst = eb; di = i4;
  } else if (i4 < S0 + S1) {
    size_t j4 = i4 - S0;
    size_t e0 = j4 * 4;
    int k = (int)(e0 & (DMODEL - 1));
    int r = (int)((e0 >> 10) & (2 * DINNER - 1));
    int l = (int)(e0 >> 22);
    const float* src = (r < DINNER)
        ? &Wres[(((size_t)l * DINNER + r) << 10) + k]
        : &Win[(((size_t)l * DINNER + (r - DINNER)) << 10) + k];
    v = *(const float4*)src;
    dst = wcatb; di = j4;
  } else if (i4 < S0 + S1 + S2) {
    size_t j4 = i4 - S0 - S1;
    v = ((const float4*)Wout)[j4];
    dst = woutb; di = j4;
  } else if (i4 < S0 + S1 + S2 + S3) {
    size_t j4 = i4 - S0 - S1 - S2;
    int k4 = (int)(j4 & (DINNER / 4 - 1));
    int row = (int)((j4 >> 9) & 127);
    int l = (int)(j4 >> 16);
    int k = k4 * 4;
    v = (float4){0.f, 0.f, 0.f, 0.f};
    if (row < 16)       v = *(const float4*)&WB[((size_t)l * DSTATE + row) * DINNER + k];
    else if (row < 32)  v = *(const float4*)&WC[((size_t)l * DSTATE + (row - 16)) * DINNER + k];
    else if (row < 96)  v = *(const float4*)&Wdt1[((size_t)l * DTRANK + (row - 32)) * DINNER + k];
    dst = wbcdtb; di = j4;
  } else if (i4 < S0 + S1 + S2 + S3 + S4) {
    size_t j4 = i4 - S0 - S1 - S2 - S3;
    v = ((const float4*)Wdt2)[j4];
    dst = wdt2b; di = j4;
  } else {
    return;
  }
  ushort4 o = {f2bf(v.x), f2bf(v.y), f2bf(v.z), f2bf(v.w)};
  ((ushort4*)dst)[di] = o;
}

// ============================================================================
extern "C" void kernel_launch(void* const* d_in, const int* in_sizes, int n_in,
                              void* d_out, int out_size, void* d_ws, size_t ws_size,
                              hipStream_t stream) {
  (void)in_sizes; (void)n_in; (void)out_size;
  const int* token_ids = (const int*)d_in[0];
  const float* embed = (const float*)d_in[1];
  const float* Wres = (const float*)d_in[2];
  const float* Win = (const float*)d_in[3];
  const float* Wconv = (const float*)d_in[4];
  const float* WB = (const float*)d_in[5];
  const float* WC = (const float*)d_in[6];
  const float* Wdt1 = (const float*)d_in[7];
  const float* Wdt2 = (const float*)d_in[8];
  const float* bdt = (const float*)d_in[9];
  const float* logA = (const float*)d_in[10];
  const float* Dp = (const float*)d_in[11];
  const float* Wout = (const float*)d_in[12];
  float* out = (float*)d_out;

  char* w = (char*)d_ws;
  auto alloc = [&](size_t bytes) {
    char* p = w;
    w += (bytes + 255) & ~(size_t)255;
    return p;
  };
  ushort* eb     = (ushort*)alloc((size_t)VOCAB * DMODEL * 2);
  ushort* wcatb  = (ushort*)alloc((size_t)NLAYER * 2 * DINNER * DMODEL * 2);
  ushort* woutb  = (ushort*)alloc((size_t)NLAYER * DMODEL * DINNER * 2);
  ushort* wbcdtb = (ushort*)alloc((size_t)NLAYER * 128 * DINNER * 2);
  ushort* wdt2b  = (ushort*)alloc((size_t)NLAYER * DINNER * DTRANK * 2);
  float* x       = (float*)alloc((size_t)SEQ * DMODEL * 4);
  ushort* xnb    = (ushort*)alloc((size_t)SEQ * DMODEL * 2);
  ushort* resu0  = (ushort*)alloc((size_t)SEQ * 2 * DINNER * 2);
  ushort* u      = (ushort*)alloc((size_t)SEQ * DINNER * 2);
  float* bcdt    = (float*)alloc((size_t)SEQ * 96 * 4);
  ushort* dtinb  = (ushort*)alloc((size_t)SEQ * 64 * 2);
  ushort* dt     = (ushort*)alloc((size_t)SEQ * DINNER * 2);
  float* Cp      = (float*)alloc((size_t)PZ * SEQ * 128 * 4);
  ushort* Cp2    = (ushort*)alloc((size_t)2 * SEQ * DMODEL * 2);
  float* Pbuf    = (float*)alloc((size_t)NCHUNK * DINNER * DSTATE * 4);
  float* Sbuf    = (float*)alloc((size_t)NCHUNK * DINNER * DSTATE * 4);
  ushort* y2b    = (ushort*)alloc((size_t)SEQ * DINNER * 2);
  ushort* xb     = (ushort*)alloc((size_t)SEQ * DMODEL * 2);
  if ((size_t)(w - (char*)d_ws) > ws_size) return;

  {
    size_t total4 = (size_t)VOCAB * DMODEL / 4
                  + (size_t)NLAYER * 2 * DINNER * DMODEL / 4
                  + (size_t)NLAYER * DMODEL * DINNER / 4
                  + (size_t)NLAYER * 128 * DINNER / 4
                  + (size_t)NLAYER * DINNER * DTRANK / 4;
    int nblk = (int)((total4 + 255) / 256);
    preproc_kernel<<<nblk, 256, 0, stream>>>(
        embed, Wres, Win, Wout, WB, WC, Wdt1, Wdt2,
        eb, wcatb, woutb, wbcdtb, wdt2b);
  }
  gather_rms_kernel<<<SEQ, 256, 0, stream>>>(token_ids, embed, x, xnb);

  for (int i = 0; i < NLAYER; ++i) {
    const ushort* wcati = wcatb + (size_t)i * 2 * DINNER * DMODEL;
    const ushort* wouti = woutb + (size_t)i * DMODEL * DINNER;
    const float* wconvi = Wconv + (size_t)i * DINNER * 4;
    const ushort* wbcdtbi = wbcdtb + (size_t)i * 128 * DINNER;
    const ushort* wdt2bi = wdt2b + (size_t)i * DINNER * DTRANK;
    const float* bdti = bdt + (size_t)i * DINNER;
    const float* logAi = logA + (size_t)i * DINNER * DSTATE;
    const float* Dpi = Dp + (size_t)i * DINNER;

    gemm2p_bt_bf16<true><<<dim3(SEQ / 128, 2 * DINNER / 128), 256, 0, stream>>>(
        xnb, wcati, resu0, 2 * DINNER, DMODEL);
    convproj_mfma<<<dim3(SEQ / 128, 1, PZ), 256, 0, stream>>>(
        resu0, wbcdtbi, wconvi, u, Cp, SEQ);
    proj_reduce<<<SEQ * 96 / 256, 256, 0, stream>>>(Cp, bcdt, dtinb, SEQ);
    gemm_dt_bf16<<<dim3(SEQ / 128, DINNER / 128), 256, 0, stream>>>(
        dtinb, wdt2bi, bdti, dt);
    dim3 gs(DINNER / 16, NCHUNK);
    scan_pass1<<<gs, 256, 0, stream>>>(dt, u, bcdt, logAi, Pbuf, Sbuf);
    scan_pass2<<<gs, 256, 0, stream>>>(dt, u, bcdt, logAi, Dpi, Pbuf, Sbuf, resu0, y2b);
    gemm_btk_bf16<<<dim3(SEQ / 128, DMODEL / 128, 2), 256, 0, stream>>>(
        y2b, wouti, Cp2, SEQ, DMODEL, DINNER);
    add3_rms_kernel<<<SEQ, 256, 0, stream>>>(
        Cp2, Cp2 + (size_t)SEQ * DMODEL, x,
        (i < NLAYER - 1) ? xnb : xb, (i < NLAYER - 1) ? 1 : 0);
  }
  gemm8p_bt_bf16<256, true><<<dim3(SEQ / 256, VOCAB / 256), 512, 0, stream>>>(
      xb, eb, out, VOCAB, DMODEL);
}

// Round 22
// 1904.468 us; speedup vs baseline: 1.0429x; 1.0037x over previous
//
#include <hip/hip_runtime.h>

#define SEQ 2048
#define DMODEL 1024
#define DINNER 2048
#define DSTATE 16
#define DTRANK 64
#define NLAYER 8
#define VOCAB 32000
#define NCHUNK 32
#define CLEN 64   // SEQ / NCHUNK
#define PZ 16     // split-K chunks for the projection GEMM

typedef float f32x4 __attribute__((ext_vector_type(4)));
typedef short bf16x8 __attribute__((ext_vector_type(8)));

__device__ __forceinline__ ushort f2bf(float f) {
  union { float f; unsigned u; } v; v.f = f;
  unsigned r = v.u + 0x7fffu + ((v.u >> 16) & 1u);
  return (ushort)(r >> 16);
}
__device__ __forceinline__ float bf2f(ushort b) {
  union { unsigned u; float f; } v; v.u = ((unsigned)b) << 16;
  return v.f;
}

__device__ __forceinline__ void lds_load16(const void* g, void* l) {
  __builtin_amdgcn_global_load_lds(
      (const __attribute__((address_space(1))) void*)g,
      (__attribute__((address_space(3))) void*)l, 16, 0, 0);
}

// ---------------- 256x256 counted-vmcnt MFMA GEMM (proven ~197us logits) ----
template<int BM, bool NTS>
__global__ __launch_bounds__(512, 2) void gemm8p_bt_bf16(
    const ushort* __restrict__ A, const ushort* __restrict__ B,
    float* __restrict__ C, int N, int K)
{
  constexpr int MFR = BM / 32;
  constexpr int MPP = MFR / 4;
  constexpr int ALOADS = BM / 128;
  __shared__ __align__(16) ushort As[2 * BM * 64];
  __shared__ __align__(16) ushort Bs[2 * 256 * 64];
  const int tid = threadIdx.x;
  const int lane = tid & 63;
  const int wid = tid >> 6;
  const int wr = wid >> 2, wc = wid & 3;
  const int rr = lane & 15, kq = lane >> 4;

  unsigned nwg = gridDim.x * gridDim.y;
  unsigned lb = blockIdx.y * gridDim.x + blockIdx.x;
  if ((nwg & 7u) == 0u) { unsigned cpx = nwg >> 3; lb = (lb & 7u) * cpx + (lb >> 3); }
  const int bm = (int)(lb % gridDim.x) * BM;
  const int bn = (int)(lb / gridDim.x) * 256;

  const ushort* Abase = A + (size_t)bm * K;
  const ushort* Bbase = B + (size_t)bn * K;

  auto stageA = [&](int buf, int h, int kt) {
    constexpr int HR = BM / 2;
#pragma unroll
    for (int L = 0; L < ALOADS; ++L) {
      int f = L * 512 + tid;
      int rl = f >> 3, g = f & 7;
      int gg = g ^ (rl & 7);
      lds_load16(Abase + (size_t)(h * HR + rl) * K + kt * 64 + gg * 8,
                 (void*)(As + buf * (BM * 64) + (h * HR + rl) * 64 + g * 8));
    }
  };
  auto stageB = [&](int buf, int h, int kt) {
#pragma unroll
    for (int L = 0; L < 2; ++L) {
      int f = L * 512 + tid;
      int rl = f >> 3, g = f & 7;
      int gg = g ^ (rl & 7);
      lds_load16(Bbase + (size_t)(h * 128 + rl) * K + kt * 64 + gg * 8,
                 (void*)(Bs + buf * (256 * 64) + (h * 128 + rl) * 64 + g * 8));
    }
  };
  auto rdA = [&](int buf, int r, int kbyte) {
    int sw = kbyte ^ ((r & 7) << 4);
    return *(const bf16x8*)(As + buf * (BM * 64) + r * 64 + (sw >> 1));
  };
  auto rdB = [&](int buf, int r, int kbyte) {
    int sw = kbyte ^ ((r & 7) << 4);
    return *(const bf16x8*)(Bs + buf * (256 * 64) + r * 64 + (sw >> 1));
  };

  f32x4 acc[MFR][4];
#pragma unroll
  for (int m = 0; m < MFR; ++m)
#pragma unroll
    for (int n = 0; n < 4; ++n) acc[m][n] = (f32x4){0.f, 0.f, 0.f, 0.f};

  const int NT = K >> 6;
  stageA(0, 0, 0); stageA(0, 1, 0); stageB(0, 0, 0); stageB(0, 1, 0);

  for (int t = 0; t < NT; ++t) {
    const int cur = t & 1;
    const bool more = (t + 1 < NT);
    if (more) stageA(cur ^ 1, 0, t + 1);
    if (more) {
      if constexpr (BM == 256) asm volatile("s_waitcnt vmcnt(2)" ::: "memory");
      else                     asm volatile("s_waitcnt vmcnt(1)" ::: "memory");
    } else {
      asm volatile("s_waitcnt vmcnt(0)" ::: "memory");
    }
    __syncthreads();

    bf16x8 bfr[4][2];
#pragma unroll
    for (int n = 0; n < 4; ++n)
#pragma unroll
      for (int kk = 0; kk < 2; ++kk)
        bfr[n][kk] = rdB(cur, wc * 64 + n * 16 + rr, kk * 64 + kq * 16);

#pragma unroll
    for (int mq = 0; mq < 4; ++mq) {
      if (mq == 1 && more) stageA(cur ^ 1, 1, t + 1);
      if (mq == 2 && more) stageB(cur ^ 1, 0, t + 1);
      if (mq == 3 && more) stageB(cur ^ 1, 1, t + 1);
      bf16x8 af[MPP][2];
#pragma unroll
      for (int mf = 0; mf < MPP; ++mf)
#pragma unroll
        for (int kk = 0; kk < 2; ++kk)
          af[mf][kk] = rdA(cur, wr * (BM / 2) + (mq * MPP + mf) * 16 + rr, kk * 64 + kq * 16);
      __builtin_amdgcn_s_setprio(1);
#pragma unroll
      for (int kk = 0; kk < 2; ++kk)
#pragma unroll
        for (int mf = 0; mf < MPP; ++mf)
#pragma unroll
          for (int n = 0; n < 4; ++n)
            acc[mq * MPP + mf][n] = __builtin_amdgcn_mfma_f32_16x16x32_bf16(
                af[mf][kk], bfr[n][kk], acc[mq * MPP + mf][n], 0, 0, 0);
      __builtin_amdgcn_s_setprio(0);
    }
    __syncthreads();
  }

  float* ep = (float*)Bs + wid * (16 * 68);
  const int cg = bn + wc * 64;
#pragma unroll
  for (int m = 0; m < MFR; ++m) {
    const int r0g = bm + wr * (BM / 2) + m * 16;
#pragma unroll
    for (int n = 0; n < 4; ++n)
#pragma unroll
      for (int j = 0; j < 4; ++j)
        ep[(kq * 4 + j) * 68 + n * 16 + rr] = acc[m][n][j];
#pragma unroll
    for (int i = 0; i < 4; ++i) {
      int row = i * 4 + kq;
      f32x4 v = *(const f32x4*)&ep[row * 68 + rr * 4];
      f32x4* dst = (f32x4*)&C[(size_t)(r0g + row) * N + cg + rr * 4];
      if constexpr (NTS) __builtin_nontemporal_store(v, dst);
      else *dst = v;
    }
  }
}

// ---------------- 128x128 2-blocks/CU MFMA GEMM (layer gemm1) ---------------
template<bool OUTBF>
__global__ __launch_bounds__(256, 2) void gemm2p_bt_bf16(
    const ushort* __restrict__ A, const ushort* __restrict__ B,
    void* __restrict__ Cv, int N, int K)
{
  __shared__ __align__(16) ushort As[2 * 128 * 64];
  __shared__ __align__(16) ushort Bs[2 * 128 * 64];
  const int tid = threadIdx.x;
  const int lane = tid & 63;
  const int wave = tid >> 6;
  const int wr = wave >> 1, wc = wave & 1;
  const int rr = lane & 15, kq = lane >> 4;

  unsigned nwg = gridDim.x * gridDim.y;
  unsigned lb = blockIdx.y * gridDim.x + blockIdx.x;
  if ((nwg & 7u) == 0u) { unsigned cpx = nwg >> 3; lb = (lb & 7u) * cpx + (lb >> 3); }
  const int bm = (int)(lb % gridDim.x) * 128;
  const int bn = (int)(lb / gridDim.x) * 128;

  const ushort* Abase = A + (size_t)bm * K;
  const ushort* Bbase = B + (size_t)bn * K;

  auto stage = [&](int buf, int kt) {
#pragma unroll
    for (int i = 0; i < 4; ++i) {
      int f = i * 256 + tid;
      int rl = f >> 3, g = f & 7;
      int gg = g ^ (rl & 7);
      lds_load16(Abase + (size_t)rl * K + kt * 64 + gg * 8,
                 (void*)(As + buf * 8192 + rl * 64 + g * 8));
      lds_load16(Bbase + (size_t)rl * K + kt * 64 + gg * 8,
                 (void*)(Bs + buf * 8192 + rl * 64 + g * 8));
    }
  };
  auto rdA = [&](int buf, int r, int kbyte) {
    int sw = kbyte ^ ((r & 7) << 4);
    return *(const bf16x8*)(As + buf * 8192 + r * 64 + (sw >> 1));
  };
  auto rdB = [&](int buf, int r, int kbyte) {
    int sw = kbyte ^ ((r & 7) << 4);
    return *(const bf16x8*)(Bs + buf * 8192 + r * 64 + (sw >> 1));
  };

  f32x4 acc[4][4];
#pragma unroll
  for (int m = 0; m < 4; ++m)
#pragma unroll
    for (int n = 0; n < 4; ++n) acc[m][n] = (f32x4){0.f, 0.f, 0.f, 0.f};

  const int NT = K >> 6;
  stage(0, 0);

  for (int t = 0; t < NT; ++t) {
    const int cur = t & 1;
    if (t + 1 < NT) {
      stage(cur ^ 1, t + 1);
      asm volatile("s_waitcnt vmcnt(8)" ::: "memory");
    } else {
      asm volatile("s_waitcnt vmcnt(0)" ::: "memory");
    }
    __syncthreads();
#pragma unroll
    for (int ks = 0; ks < 2; ++ks) {
      const int kbyte = ks * 64 + kq * 16;
      bf16x8 af[4], bfr[4];
#pragma unroll
      for (int m = 0; m < 4; ++m)
        af[m] = rdA(cur, wr * 64 + m * 16 + rr, kbyte);
#pragma unroll
      for (int n = 0; n < 4; ++n)
        bfr[n] = rdB(cur, wc * 64 + n * 16 + rr, kbyte);
      __builtin_amdgcn_s_setprio(1);
#pragma unroll
      for (int m = 0; m < 4; ++m)
#pragma unroll
        for (int n = 0; n < 4; ++n)
          acc[m][n] = __builtin_amdgcn_mfma_f32_16x16x32_bf16(af[m], bfr[n], acc[m][n], 0, 0, 0);
      __builtin_amdgcn_s_setprio(0);
    }
    __syncthreads();
  }

  float* ep = (float*)Bs + wave * (16 * 68);
  const int cg = bn + wc * 64;
#pragma unroll
  for (int m = 0; m < 4; ++m) {
    const int r0g = bm + wr * 64 + m * 16;
#pragma unroll
    for (int n = 0; n < 4; ++n)
#pragma unroll
      for (int j = 0; j < 4; ++j)
        ep[(kq * 4 + j) * 68 + n * 16 + rr] = acc[m][n][j];
#pragma unroll
    for (int i = 0; i < 4; ++i) {
      int row = i * 4 + kq;
      f32x4 v = *(const f32x4*)&ep[row * 68 + rr * 4];
      if constexpr (OUTBF) {
        ushort* C = (ushort*)Cv;
        ushort4 o = {f2bf(v.x), f2bf(v.y), f2bf(v.z), f2bf(v.w)};
        *(ushort4*)&C[(size_t)(r0g + row) * N + cg + rr * 4] = o;
      } else {
        float* C = (float*)Cv;
        *(f32x4*)&C[(size_t)(r0g + row) * N + cg + rr * 4] = v;
      }
    }
  }
}

// ---- split-K bf16 MFMA GEMM (2-phase 128x128, T2 swizzle, bf16 partials) ---
__global__ __launch_bounds__(256) void gemm_btk_bf16(
    const ushort* __restrict__ A, const ushort* __restrict__ B,
    ushort* __restrict__ Cp, int M, int N, int K)
{
  __shared__ __align__(16) ushort As[128 * 64];
  __shared__ __align__(16) ushort Bs[128 * 64];
  const int tid = threadIdx.x;
  const int lane = tid & 63;
  const int wave = tid >> 6;
  const int wr = wave >> 1, wc = wave & 1;
  const int KC = K / gridDim.z;
  const int k0 = blockIdx.z * KC;

  unsigned nwg = gridDim.x * gridDim.y;
  unsigned lb = blockIdx.y * gridDim.x + blockIdx.x;
  if ((nwg & 7u) == 0u) {
    unsigned cpx = nwg >> 3;
    lb = (lb & 7u) * cpx + (lb >> 3);
  }
  const int bm = (lb % gridDim.x) * 128;
  const int bn = (lb / gridDim.x) * 128;
  const int rr = lane & 15, kq = lane >> 4;

  auto rdA = [&](int r, int kbyte) {
    int sw = kbyte ^ ((r & 7) << 4);
    return *(const bf16x8*)(As + r * 64 + (sw >> 1));
  };
  auto rdB = [&](int r, int kbyte) {
    int sw = kbyte ^ ((r & 7) << 4);
    return *(const bf16x8*)(Bs + r * 64 + (sw >> 1));
  };

  f32x4 acc[4][4];
#pragma unroll
  for (int m = 0; m < 4; ++m)
#pragma unroll
    for (int n = 0; n < 4; ++n) acc[m][n] = (f32x4){0.f, 0.f, 0.f, 0.f};

  for (int kt = 0; kt < KC; kt += 64) {
#pragma unroll
    for (int i = 0; i < 4; ++i) {
      int fb = i * 256 + tid;
      int row = fb >> 3, g = fb & 7;
      int gg = g ^ (row & 7);
      lds_load16(A + (size_t)(bm + row) * K + k0 + kt + gg * 8, (void*)(As + (size_t)fb * 8));
      lds_load16(B + (size_t)(bn + row) * K + k0 + kt + gg * 8, (void*)(Bs + (size_t)fb * 8));
    }
    asm volatile("s_waitcnt vmcnt(0)" ::: "memory");
    __syncthreads();
#pragma unroll
    for (int ks = 0; ks < 2; ++ks) {
      const int kbyte = ks * 64 + kq * 16;
      bf16x8 af[4], bfr[4];
#pragma unroll
      for (int m = 0; m < 4; ++m)
        af[m] = rdA(wr * 64 + m * 16 + rr, kbyte);
#pragma unroll
      for (int n = 0; n < 4; ++n)
        bfr[n] = rdB(wc * 64 + n * 16 + rr, kbyte);
#pragma unroll
      for (int m = 0; m < 4; ++m)
#pragma unroll
        for (int n = 0; n < 4; ++n)
          acc[m][n] = __builtin_amdgcn_mfma_f32_16x16x32_bf16(af[m], bfr[n], acc[m][n], 0, 0, 0);
    }
    __syncthreads();
  }
  ushort* C = Cp + (size_t)blockIdx.z * M * N;
#pragma unroll
  for (int m = 0; m < 4; ++m) {
    const int r0 = bm + wr * 64 + m * 16 + kq * 4;
#pragma unroll
    for (int n = 0; n < 4; ++n) {
      const int cc = bn + wc * 64 + n * 16 + rr;
#pragma unroll
      for (int j = 0; j < 4; ++j)
        C[(size_t)(r0 + j) * N + cc] = f2bf(acc[m][n][j]);
    }
  }
}

// ---------------- fused conv+SiLU + split-K MFMA projection (T2 swizzle) ----
// bf16 partials: Cp[z][M][128] as ushort.
__global__ __launch_bounds__(256) void convproj_mfma(
    const ushort* __restrict__ resu0, const ushort* __restrict__ W,
    const float* __restrict__ Wconv, ushort* __restrict__ u,
    ushort* __restrict__ Cp, int M)
{
  __shared__ __align__(16) ushort u0s[131][128];
  __shared__ __align__(16) ushort As[2][128 * 64];
  __shared__ __align__(16) ushort Bs[2][128 * 64];
  const int tid = threadIdx.x;
  const int lane = tid & 63;
  const int wave = tid >> 6;
  const int wr = wave >> 1, wc = wave & 1;
  const int rr = lane & 15, kq = lane >> 4;
  const int bm = blockIdx.x * 128;
  const int kc = blockIdx.z * 128;

#pragma unroll
  for (int h = 0; h < 2; ++h)
#pragma unroll
    for (int i = 0; i < 4; ++i) {
      int f = i * 256 + tid;
      int rl = f >> 3, g = f & 7;
      int gg = g ^ (rl & 7);
      lds_load16(W + (size_t)rl * DINNER + kc + h * 64 + gg * 8,
                 (void*)(&Bs[h][rl * 64 + g * 8]));
    }

  for (int i = tid; i < 131 * 32; i += 256) {
    int row = i >> 5, c4 = (i & 31) * 4;
    int gr = bm - 3 + row;
    ushort4 v = {0, 0, 0, 0};
    if (gr >= 0)
      v = *(const ushort4*)&resu0[(size_t)gr * (2 * DINNER) + DINNER + kc + c4];
    *(ushort4*)&u0s[row][c4] = v;
  }
  __syncthreads();

  {
    const int c0 = (tid & 31) * 4;
    const int r0 = (tid >> 5) * 16;
    float4 w0 = *(const float4*)&Wconv[(kc + c0 + 0) * 4];
    float4 w1 = *(const float4*)&Wconv[(kc + c0 + 1) * 4];
    float4 w2 = *(const float4*)&Wconv[(kc + c0 + 2) * 4];
    float4 w3 = *(const float4*)&Wconv[(kc + c0 + 3) * 4];
    const int ks = c0 >> 6;
    const int cl = c0 & 63;
    for (int r = r0; r < r0 + 16; ++r) {
      ushort4 a0 = *(const ushort4*)&u0s[r + 0][c0];
      ushort4 a1 = *(const ushort4*)&u0s[r + 1][c0];
      ushort4 a2 = *(const ushort4*)&u0s[r + 2][c0];
      ushort4 a3 = *(const ushort4*)&u0s[r + 3][c0];
      float o0 = bf2f(a0.x) * w0.x + bf2f(a1.x) * w0.y + bf2f(a2.x) * w0.z + bf2f(a3.x) * w0.w;
      float o1 = bf2f(a0.y) * w1.x + bf2f(a1.y) * w1.y + bf2f(a2.y) * w1.z + bf2f(a3.y) * w1.w;
      float o2 = bf2f(a0.z) * w2.x + bf2f(a1.z) * w2.y + bf2f(a2.z) * w2.z + bf2f(a3.z) * w2.w;
      float o3 = bf2f(a0.w) * w3.x + bf2f(a1.w) * w3.y + bf2f(a2.w) * w3.z + bf2f(a3.w) * w3.w;
      o0 = o0 / (1.f + expf(-o0));
      o1 = o1 / (1.f + expf(-o1));
      o2 = o2 / (1.f + expf(-o2));
      o3 = o3 / (1.f + expf(-o3));
      ushort4 o = {f2bf(o0), f2bf(o1), f2bf(o2), f2bf(o3)};
      int sg = ((cl >> 3) ^ (r & 7)) * 8 + (cl & 7);
      *(ushort4*)&As[ks][r * 64 + sg] = o;
      *(ushort4*)&u[(size_t)(bm + r) * DINNER + kc + c0] = o;
    }
  }
  asm volatile("s_waitcnt vmcnt(0)" ::: "memory");
  __syncthreads();

  f32x4 acc[4][4];
#pragma unroll
  for (int m = 0; m < 4; ++m)
#pragma unroll
    for (int n = 0; n < 4; ++n) acc[m][n] = (f32x4){0.f, 0.f, 0.f, 0.f};

#pragma unroll
  for (int ks = 0; ks < 2; ++ks) {
#pragma unroll
    for (int kk = 0; kk < 2; ++kk) {
      const int kbyte = kk * 64 + kq * 16;
      bf16x8 af[4], bfr[4];
#pragma unroll
      for (int m = 0; m < 4; ++m) {
        int r = wr * 64 + m * 16 + rr;
        int sw = kbyte ^ ((r & 7) << 4);
        af[m] = *(const bf16x8*)&As[ks][r * 64 + (sw >> 1)];
      }
#pragma unroll
      for (int n = 0; n < 4; ++n) {
        int r = wc * 64 + n * 16 + rr;
        int sw = kbyte ^ ((r & 7) << 4);
        bfr[n] = *(const bf16x8*)&Bs[ks][r * 64 + (sw >> 1)];
      }
      __builtin_amdgcn_s_setprio(1);
#pragma unroll
      for (int m = 0; m < 4; ++m)
#pragma unroll
        for (int n = 0; n < 4; ++n)
          acc[m][n] = __builtin_amdgcn_mfma_f32_16x16x32_bf16(af[m], bfr[n], acc[m][n], 0, 0, 0);
      __builtin_amdgcn_s_setprio(0);
    }
  }

  ushort* C = Cp + (size_t)blockIdx.z * M * 128;
#pragma unroll
  for (int m = 0; m < 4; ++m) {
    const int r0 = bm + wr * 64 + m * 16 + kq * 4;
#pragma unroll
    for (int n = 0; n < 4; ++n) {
      const int cc = wc * 64 + n * 16 + rr;
#pragma unroll
      for (int j = 0; j < 4; ++j)
        C[(size_t)(r0 + j) * 128 + cc] = f2bf(acc[m][n][j]);
    }
  }
}

// ---------------- dt GEMM (K=64, bf16 dtin input, T2 swizzle) ---------------
__global__ __launch_bounds__(256) void gemm_dt_bf16(
    const ushort* __restrict__ A, const ushort* __restrict__ W,
    const float* __restrict__ bias, ushort* __restrict__ dt)
{
  __shared__ __align__(16) ushort As[128 * 64];
  __shared__ __align__(16) ushort Bs[128 * 64];
  __shared__ float eps[4 * 16 * 68];
  const int tid = threadIdx.x;
  const int lane = tid & 63;
  const int wave = tid >> 6;
  const int wr = wave >> 1, wc = wave & 1;
  const int rr = lane & 15, kq = lane >> 4;
  const int bm = blockIdx.x * 128;
  const int bn = blockIdx.y * 128;

#pragma unroll
  for (int i = 0; i < 4; ++i) {
    int f = i * 256 + tid;
    int rl = f >> 3, g = f & 7;
    int gg = g ^ (rl & 7);
    lds_load16(A + (size_t)(bm + rl) * DTRANK + gg * 8, (void*)(As + (size_t)f * 8));
    lds_load16(W + (size_t)(bn + rl) * DTRANK + gg * 8, (void*)(Bs + (size_t)f * 8));
  }
  asm volatile("s_waitcnt vmcnt(0)" ::: "memory");
  __syncthreads();

  f32x4 acc[4][4];
#pragma unroll
  for (int m = 0; m < 4; ++m)
#pragma unroll
    for (int n = 0; n < 4; ++n) acc[m][n] = (f32x4){0.f, 0.f, 0.f, 0.f};

#pragma unroll
  for (int ks = 0; ks < 2; ++ks) {
    const int kbyte = ks * 64 + kq * 16;
    bf16x8 af[4], bfr[4];
#pragma unroll
    for (int m = 0; m < 4; ++m) {
      int r = wr * 64 + m * 16 + rr;
      int sw = kbyte ^ ((r & 7) << 4);
      af[m] = *(const bf16x8*)&As[r * 64 + (sw >> 1)];
    }
#pragma unroll
    for (int n = 0; n < 4; ++n) {
      int r = wc * 64 + n * 16 + rr;
      int sw = kbyte ^ ((r & 7) << 4);
      bfr[n] = *(const bf16x8*)&Bs[r * 64 + (sw >> 1)];
    }
#pragma unroll
    for (int m = 0; m < 4; ++m)
#pragma unroll
      for (int n = 0; n < 4; ++n)
        acc[m][n] = __builtin_amdgcn_mfma_f32_16x16x32_bf16(af[m], bfr[n], acc[m][n], 0, 0, 0);
  }
  __syncthreads();

  float* ep = eps + wave * (16 * 68);
  const int cgb = bn + wc * 64 + rr * 4;
  float4 b4 = *(const float4*)&bias[cgb];
#pragma unroll
  for (int m = 0; m < 4; ++m) {
    const int r0g = bm + wr * 64 + m * 16;
#pragma unroll
    for (int n = 0; n < 4; ++n)
#pragma unroll
      for (int j = 0; j < 4; ++j)
        ep[(kq * 4 + j) * 68 + n * 16 + rr] = acc[m][n][j];
#pragma unroll
    for (int i = 0; i < 4; ++i) {
      int row = i * 4 + kq;
      f32x4 v = *(const f32x4*)&ep[row * 68 + rr * 4];
      float v0 = v.x + b4.x, v1 = v.y + b4.y, v2 = v.z + b4.z, v3 = v.w + b4.w;
      v0 = (v0 > 20.f) ? v0 : log1pf(expf(v0));
      v1 = (v1 > 20.f) ? v1 : log1pf(expf(v1));
      v2 = (v2 > 20.f) ? v2 : log1pf(expf(v2));
      v3 = (v3 > 20.f) ? v3 : log1pf(expf(v3));
      ushort4 o = {f2bf(v0), f2bf(v1), f2bf(v2), f2bf(v3)};
      *(ushort4*)&dt[(size_t)(r0g + row) * DINNER + cgb] = o;
    }
  }
}

// ---- x += P0 + P1 (bf16 partials), then RMSNorm(x)->bf16 (or plain cast) ---
__global__ __launch_bounds__(256) void add3_rms_kernel(
    const ushort* __restrict__ P0, const ushort* __restrict__ P1,
    float* __restrict__ x, ushort* __restrict__ dst, int donorm)
{
  size_t o = (size_t)blockIdx.x * (DMODEL / 4) + threadIdx.x;
  ushort4 a = ((const ushort4*)P0)[o];
  ushort4 b = ((const ushort4*)P1)[o];
  float4 c = ((float4*)x)[o];
  c.x += bf2f(a.x) + bf2f(b.x);
  c.y += bf2f(a.y) + bf2f(b.y);
  c.z += bf2f(a.z) + bf2f(b.z);
  c.w += bf2f(a.w) + bf2f(b.w);
  ((float4*)x)[o] = c;
  float sc = 1.f;
  if (donorm) {
    float s = c.x * c.x + c.y * c.y + c.z * c.z + c.w * c.w;
#pragma unroll
    for (int off = 32; off > 0; off >>= 1) s += __shfl_down(s, off);
    __shared__ float ws[4];
    if ((threadIdx.x & 63) == 0) ws[threadIdx.x >> 6] = s;
    __syncthreads();
    float tot = ws[0] + ws[1] + ws[2] + ws[3];
    sc = rsqrtf(tot * (1.0f / DMODEL) + 1e-6f);
  }
  ushort4 o4 = {f2bf(c.x * sc), f2bf(c.y * sc), f2bf(c.z * sc), f2bf(c.w * sc)};
  ((ushort4*)dst)[o] = o4;
}

// ---------------- embedding gather + RMSNorm -> x (f32) and xnb (bf16) ------
__global__ __launch_bounds__(256) void gather_rms_kernel(
    const int* __restrict__ ids, const float* __restrict__ embed,
    float* __restrict__ x, ushort* __restrict__ xnb)
{
  int row = blockIdx.x;
  int id = ids[row];
  float4 v = ((const float4*)(embed + (size_t)id * DMODEL))[threadIdx.x];
  size_t o = (size_t)row * (DMODEL / 4) + threadIdx.x;
  ((float4*)x)[o] = v;
  float s = v.x * v.x + v.y * v.y + v.z * v.z + v.w * v.w;
#pragma unroll
  for (int off = 32; off > 0; off >>= 1) s += __shfl_down(s, off);
  __shared__ float ws[4];
  if ((threadIdx.x & 63) == 0) ws[threadIdx.x >> 6] = s;
  __syncthreads();
  float tot = ws[0] + ws[1] + ws[2] + ws[3];
  float sc = rsqrtf(tot * (1.0f / DMODEL) + 1e-6f);
  ushort4 o4 = {f2bf(v.x * sc), f2bf(v.y * sc), f2bf(v.z * sc), f2bf(v.w * sc)};
  ((ushort4*)xnb)[o] = o4;
}

// ---- proj reduce (bf16 partials): B/C -> bcdt f32, dt-in -> dtinb bf16 -----
__global__ __launch_bounds__(256) void proj_reduce(
    const ushort* __restrict__ Cp, float* __restrict__ bcdt,
    ushort* __restrict__ dtinb, int M)
{
  int idx = blockIdx.x * 256 + threadIdx.x;
  int row = idx / 96, col = idx - row * 96;
  float s = 0.f;
#pragma unroll
  for (int c = 0; c < PZ; ++c)
    s += bf2f(Cp[(size_t)c * M * 128 + (size_t)row * 128 + col]);
  if (col < 32) bcdt[(size_t)row * 96 + col] = s;
  else dtinb[(size_t)row * 64 + (col - 32)] = f2bf(s);
}

// ---------------- chunk-parallel selective scan (bf16 dt/u inputs) ----------
__global__ __launch_bounds__(256) void scan_pass1(
    const ushort* __restrict__ dt, const ushort* __restrict__ u,
    const float* __restrict__ bcdt, const float* __restrict__ logA,
    float* __restrict__ P, float* __restrict__ S)
{
  const int tid = threadIdx.x;
  const int n = tid & 15, dl = tid >> 4;
  const int dbase = blockIdx.x * 16;
  const int c = blockIdx.y;
  const int t0 = c * CLEN;
  const int d = dbase + dl;
  const float Aval = -expf(logA[d * DSTATE + n]);
  __shared__ float sdt[CLEN][16], su[CLEN][16], sB[CLEN][16];
  {
    int tt = tid >> 2, j0 = (tid & 3) * 4;
    ushort4 rd = *(const ushort4*)&dt[(size_t)(t0 + tt) * DINNER + dbase + j0];
    ushort4 ru = *(const ushort4*)&u[(size_t)(t0 + tt) * DINNER + dbase + j0];
    sdt[tt][j0 + 0] = bf2f(rd.x); sdt[tt][j0 + 1] = bf2f(rd.y);
    sdt[tt][j0 + 2] = bf2f(rd.z); sdt[tt][j0 + 3] = bf2f(rd.w);
    su[tt][j0 + 0] = bf2f(ru.x); su[tt][j0 + 1] = bf2f(ru.y);
    su[tt][j0 + 2] = bf2f(ru.z); su[tt][j0 + 3] = bf2f(ru.w);
    *(float4*)&sB[tt][j0] = *(const float4*)&bcdt[(size_t)(t0 + tt) * 96 + j0];
  }
  __syncthreads();
  float h = 0.f, pr = 1.f;
#pragma unroll 8
  for (int i = 0; i < CLEN; ++i) {
    float dtv = sdt[i][dl], uv = su[i][dl], Bv = sB[i][n];
    float dtA = dtv * Aval;
    float rinv = __builtin_amdgcn_rcpf(1.f - 0.5f * dtA);
    float dA = (1.f + 0.5f * dtA) * rinv;
    float dBu = dtv * Bv * rinv * uv;
    h = dA * h + dBu;
    pr *= dA;
  }
  size_t idx = (size_t)c * (DINNER * DSTATE) + (size_t)d * DSTATE + n;
  P[idx] = pr;
  S[idx] = h;
}

__global__ __launch_bounds__(256) void scan_pass2(
    const ushort* __restrict__ dt, const ushort* __restrict__ u,
    const float* __restrict__ bcdt, const float* __restrict__ logA,
    const float* __restrict__ Dp, const float* __restrict__ P,
    const float* __restrict__ S, const ushort* __restrict__ resu0,
    ushort* __restrict__ y2b)
{
  const int tid = threadIdx.x;
  const int n = tid & 15, dl = tid >> 4;
  const int dbase = blockIdx.x * 16;
  const int c = blockIdx.y;
  const int t0 = c * CLEN;
  const int d = dbase + dl;
  const float Aval = -expf(logA[d * DSTATE + n]);
  const float Dpv = Dp[d];
  __shared__ float sdt[CLEN][16], su[CLEN][16], sB[CLEN][16], sC[CLEN][16], sres[CLEN][16];
  {
    int tt = tid >> 2, j0 = (tid & 3) * 4;
    ushort4 rd = *(const ushort4*)&dt[(size_t)(t0 + tt) * DINNER + dbase + j0];
    ushort4 ru = *(const ushort4*)&u[(size_t)(t0 + tt) * DINNER + dbase + j0];
    ushort4 rr4 = *(const ushort4*)&resu0[(size_t)(t0 + tt) * (2 * DINNER) + dbase + j0];
    sdt[tt][j0 + 0] = bf2f(rd.x); sdt[tt][j0 + 1] = bf2f(rd.y);
    sdt[tt][j0 + 2] = bf2f(rd.z); sdt[tt][j0 + 3] = bf2f(rd.w);
    su[tt][j0 + 0] = bf2f(ru.x); su[tt][j0 + 1] = bf2f(ru.y);
    su[tt][j0 + 2] = bf2f(ru.z); su[tt][j0 + 3] = bf2f(ru.w);
    sres[tt][j0 + 0] = bf2f(rr4.x); sres[tt][j0 + 1] = bf2f(rr4.y);
    sres[tt][j0 + 2] = bf2f(rr4.z); sres[tt][j0 + 3] = bf2f(rr4.w);
    *(float4*)&sB[tt][j0] = *(const float4*)&bcdt[(size_t)(t0 + tt) * 96 + j0];
    *(float4*)&sC[tt][j0] = *(const float4*)&bcdt[(size_t)(t0 + tt) * 96 + 16 + j0];
  }
  float h = 0.f;
  {
    const size_t base = (size_t)d * DSTATE + n;
#pragma unroll 4
    for (int cc = 0; cc < c; ++cc) {
      size_t o = (size_t)cc * (DINNER * DSTATE) + base;
      h = P[o] * h + S[o];
    }
  }
  __syncthreads();
#pragma unroll 4
  for (int i = 0; i < CLEN; ++i) {
    float dtv = sdt[i][dl], uv = su[i][dl];
    float dtA = dtv * Aval;
    float rinv = __builtin_amdgcn_rcpf(1.f - 0.5f * dtA);
    float dA = (1.f + 0.5f * dtA) * rinv;
    float dBu = dtv * sB[i][n] * rinv * uv;
    h = dA * h + dBu;
    float p = h * sC[i][n];
    p += __shfl_xor(p, 1);
    p += __shfl_xor(p, 2);
    p += __shfl_xor(p, 4);
    p += __shfl_xor(p, 8);
    if (n == 0) {
      float rv = sres[i][dl];
      float yv = (p + uv * Dpv) * (rv / (1.f + expf(-rv)));
      y2b[(size_t)(t0 + i) * DINNER + d] = f2bf(yv);
    }
  }
}

// ---------------- unified weight preprocessing (one launch) -----------------
__global__ __launch_bounds__(256) void preproc_kernel(
    const float* __restrict__ embed, const float* __restrict__ Wres,
    const float* __restrict__ Win, const float* __restrict__ Wout,
    const float* __restrict__ WB, const float* __restrict__ WC,
    const float* __restrict__ Wdt1, const float* __restrict__ Wdt2,
    ushort* __restrict__ eb, ushort* __restrict__ wcatb,
    ushort* __restrict__ woutb, ushort* __restrict__ wbcdtb,
    ushort* __restrict__ wdt2b)
{
  const size_t S0 = (size_t)VOCAB * DMODEL / 4;
  const size_t S1 = (size_t)NLAYER * 2 * DINNER * DMODEL / 4;
  const size_t S2 = (size_t)NLAYER * DMODEL * DINNER / 4;
  const size_t S3 = (size_t)NLAYER * 128 * DINNER / 4;
  const size_t S4 = (size_t)NLAYER * DINNER * DTRANK / 4;
  size_t i4 = (size_t)blockIdx.x * 256 + threadIdx.x;
  float4 v;
  ushort* dst;
  size_t di;
  if (i4 < S0) {
    v = ((const float4*)embed)[i4];
    dst = eb; di = i4;
  } else if (i4 < S0 + S1) {
    size_t j4 = i4 - S0;
    size_t e0 = j4 * 4;
    int k = (int)(e0 & (DMODEL - 1));
    int r = (int)((e0 >> 10) & (2 * DINNER - 1));
    int l = (int)(e0 >> 22);
    const float* src = (r < DINNER)
        ? &Wres[(((size_t)l * DINNER + r) << 10) + k]
        : &Win[(((size_t)l * DINNER + (r - DINNER)) << 10) + k];
    v = *(const float4*)src;
    dst = wcatb; di = j4;
  } else if (i4 < S0 + S1 + S2) {
    size_t j4 = i4 - S0 - S1;
    v = ((const float4*)Wout)[j4];
    dst = woutb; di = j4;
  } else if (i4 < S0 + S1 + S2 + S3) {
    size_t j4 = i4 - S0 - S1 - S2;
    int k4 = (int)(j4 & (DINNER / 4 - 1));
    int row = (int)((j4 >> 9) & 127);
    int l = (int)(j4 >> 16);
    int k = k4 * 4;
    v = (float4){0.f, 0.f, 0.f, 0.f};
    if (row < 16)       v = *(const float4*)&WB[((size_t)l * DSTATE + row) * DINNER + k];
    else if (row < 32)  v = *(const float4*)&WC[((size_t)l * DSTATE + (row - 16)) * DINNER + k];
    else if (row < 96)  v = *(const float4*)&Wdt1[((size_t)l * DTRANK + (row - 32)) * DINNER + k];
    dst = wbcdtb; di = j4;
  } else if (i4 < S0 + S1 + S2 + S3 + S4) {
    size_t j4 = i4 - S0 - S1 - S2 - S3;
    v = ((const float4*)Wdt2)[j4];
    dst = wdt2b; di = j4;
  } else {
    return;
  }
  ushort4 o = {f2bf(v.x), f2bf(v.y), f2bf(v.z), f2bf(v.w)};
  ((ushort4*)dst)[di] = o;
}

// ============================================================================
extern "C" void kernel_launch(void* const* d_in, const int* in_sizes, int n_in,
                              void* d_out, int out_size, void* d_ws, size_t ws_size,
                              hipStream_t stream) {
  (void)in_sizes; (void)n_in; (void)out_size;
  const int* token_ids = (const int*)d_in[0];
  const float* embed = (const float*)d_in[1];
  const float* Wres = (const float*)d_in[2];
  const float* Win = (const float*)d_in[3];
  const float* Wconv = (const float*)d_in[4];
  const float* WB = (const float*)d_in[5];
  const float* WC = (const float*)d_in[6];
  const float* Wdt1 = (const float*)d_in[7];
  const float* Wdt2 = (const float*)d_in[8];
  const float* bdt = (const float*)d_in[9];
  const float* logA = (const float*)d_in[10];
  const float* Dp = (const float*)d_in[11];
  const float* Wout = (const float*)d_in[12];
  float* out = (float*)d_out;

  char* w = (char*)d_ws;
  auto alloc = [&](size_t bytes) {
    char* p = w;
    w += (bytes + 255) & ~(size_t)255;
    return p;
  };
  ushort* eb     = (ushort*)alloc((size_t)VOCAB * DMODEL * 2);
  ushort* wcatb  = (ushort*)alloc((size_t)NLAYER * 2 * DINNER * DMODEL * 2);
  ushort* woutb  = (ushort*)alloc((size_t)NLAYER * DMODEL * DINNER * 2);
  ushort* wbcdtb = (ushort*)alloc((size_t)NLAYER * 128 * DINNER * 2);
  ushort* wdt2b  = (ushort*)alloc((size_t)NLAYER * DINNER * DTRANK * 2);
  float* x       = (float*)alloc((size_t)SEQ * DMODEL * 4);
  ushort* xnb    = (ushort*)alloc((size_t)SEQ * DMODEL * 2);
  ushort* resu0  = (ushort*)alloc((size_t)SEQ * 2 * DINNER * 2);
  ushort* u      = (ushort*)alloc((size_t)SEQ * DINNER * 2);
  float* bcdt    = (float*)alloc((size_t)SEQ * 96 * 4);
  ushort* dtinb  = (ushort*)alloc((size_t)SEQ * 64 * 2);
  ushort* dt     = (ushort*)alloc((size_t)SEQ * DINNER * 2);
  ushort* Cp     = (ushort*)alloc((size_t)PZ * SEQ * 128 * 2);
  ushort* Cp2    = (ushort*)alloc((size_t)2 * SEQ * DMODEL * 2);
  float* Pbuf    = (float*)alloc((size_t)NCHUNK * DINNER * DSTATE * 4);
  float* Sbuf    = (float*)alloc((size_t)NCHUNK * DINNER * DSTATE * 4);
  ushort* y2b    = (ushort*)alloc((size_t)SEQ * DINNER * 2);
  ushort* xb     = (ushort*)alloc((size_t)SEQ * DMODEL * 2);
  if ((size_t)(w - (char*)d_ws) > ws_size) return;

  {
    size_t total4 = (size_t)VOCAB * DMODEL / 4
                  + (size_t)NLAYER * 2 * DINNER * DMODEL / 4
                  + (size_t)NLAYER * DMODEL * DINNER / 4
                  + (size_t)NLAYER * 128 * DINNER / 4
                  + (size_t)NLAYER * DINNER * DTRANK / 4;
    int nblk = (int)((total4 + 255) / 256);
    preproc_kernel<<<nblk, 256, 0, stream>>>(
        embed, Wres, Win, Wout, WB, WC, Wdt1, Wdt2,
        eb, wcatb, woutb, wbcdtb, wdt2b);
  }
  gather_rms_kernel<<<SEQ, 256, 0, stream>>>(token_ids, embed, x, xnb);

  for (int i = 0; i < NLAYER; ++i) {
    const ushort* wcati = wcatb + (size_t)i * 2 * DINNER * DMODEL;
    const ushort* wouti = woutb + (size_t)i * DMODEL * DINNER;
    const float* wconvi = Wconv + (size_t)i * DINNER * 4;
    const ushort* wbcdtbi = wbcdtb + (size_t)i * 128 * DINNER;
    const ushort* wdt2bi = wdt2b + (size_t)i * DINNER * DTRANK;
    const float* bdti = bdt + (size_t)i * DINNER;
    const float* logAi = logA + (size_t)i * DINNER * DSTATE;
    const float* Dpi = Dp + (size_t)i * DINNER;

    gemm2p_bt_bf16<true><<<dim3(SEQ / 128, 2 * DINNER / 128), 256, 0, stream>>>(
        xnb, wcati, resu0, 2 * DINNER, DMODEL);
    convproj_mfma<<<dim3(SEQ / 128, 1, PZ), 256, 0, stream>>>(
        resu0, wbcdtbi, wconvi, u, Cp, SEQ);
    proj_reduce<<<SEQ * 96 / 256, 256, 0, stream>>>(Cp, bcdt, dtinb, SEQ);
    gemm_dt_bf16<<<dim3(SEQ / 128, DINNER / 128), 256, 0, stream>>>(
        dtinb, wdt2bi, bdti, dt);
    dim3 gs(DINNER / 16, NCHUNK);
    scan_pass1<<<gs, 256, 0, stream>>>(dt, u, bcdt, logAi, Pbuf, Sbuf);
    scan_pass2<<<gs, 256, 0, stream>>>(dt, u, bcdt, logAi, Dpi, Pbuf, Sbuf, resu0, y2b);
    gemm_btk_bf16<<<dim3(SEQ / 128, DMODEL / 128, 2), 256, 0, stream>>>(
        y2b, wouti, Cp2, SEQ, DMODEL, DINNER);
    add3_rms_kernel<<<SEQ, 256, 0, stream>>>(
        Cp2, Cp2 + (size_t)SEQ * DMODEL, x,
        (i < NLAYER - 1) ? xnb : xb, (i < NLAYER - 1) ? 1 : 0);
  }
  gemm8p_bt_bf16<256, true><<<dim3(SEQ / 256, VOCAB / 256), 512, 0, stream>>>(
      xb, eb, out, VOCAB, DMODEL);
}